// Round 1
// baseline (1472.452 us; speedup 1.0000x reference)
//
#include <hip/hip_runtime.h>

// TRGTMeanRelationBlock: graph message-passing block on MI355X (gfx950).
// Pipeline: prep(weights->bf16 W^T) ; ln1 ; memset(agg,deg) ; edge ; node1 ; ln2 ; ffn
// All heavy GEMMs via v_mfma_f32_16x16x32_bf16.
// Fragment layouts: A/B lane l -> (row/col = l&15, 8 contiguous k at (l>>4)*8).
//                   C/D lane l -> col = l&15, row = (l>>4)*4 + reg_idx.

typedef __attribute__((ext_vector_type(8))) short short8;
typedef __attribute__((ext_vector_type(4))) float f32x4;

#define NN 50000
#define NEDGE 800000

#define MFMA(a, b, c) __builtin_amdgcn_mfma_f32_16x16x32_bf16(a, b, c, 0, 0, 0)

__device__ __forceinline__ unsigned short f2bf(float f) {
  unsigned int u = __float_as_uint(f);
  u += 0x7fffu + ((u >> 16) & 1u);   // round-to-nearest-even
  return (unsigned short)(u >> 16);
}
__device__ __forceinline__ float geluf(float x) {
  return 0.5f * x * (1.0f + erff(x * 0.70710678118654752f));
}
__device__ __forceinline__ short8 ld8(const unsigned short* p) {
  return *reinterpret_cast<const short8*>(p);
}
__device__ __forceinline__ short8 cvt8(const float* p) {
  const f32x4 a = *reinterpret_cast<const f32x4*>(p);
  const f32x4 b = *reinterpret_cast<const f32x4*>(p + 4);
  short8 r;
  r[0] = (short)f2bf(a[0]); r[1] = (short)f2bf(a[1]);
  r[2] = (short)f2bf(a[2]); r[3] = (short)f2bf(a[3]);
  r[4] = (short)f2bf(b[0]); r[5] = (short)f2bf(b[1]);
  r[6] = (short)f2bf(b[2]); r[7] = (short)f2bf(b[3]);
  return r;
}

// ---- weight prep: transpose + f32->bf16. WT[n][k] = W[k][n].
// ws ushort offsets: selfWT 0 (16384) | aggWT 16384 (16384) | msgW1T 32768 (24576,K=192)
// | msgW2T 57344 (16384) | gateW1T 73728 (40960,K=320) | ffnW1T 114688 (32768,K=128,N=256)
// | ffnW2T 147456 (32768,K=256,N=128)  -- total 180224 ushorts.
__global__ __launch_bounds__(256) void prep_kernel(
    const float* __restrict__ selfW, const float* __restrict__ msgW1,
    const float* __restrict__ msgW2, const float* __restrict__ gateW1,
    const float* __restrict__ aggW, const float* __restrict__ ffnW1,
    const float* __restrict__ ffnW2, unsigned short* __restrict__ wts) {
  const int idx = blockIdx.x * 256 + threadIdx.x;
  if (idx < 16384) {
    int n = idx >> 7, k = idx & 127;
    wts[idx] = f2bf(selfW[k * 128 + n]);
  } else if (idx < 32768) {
    int l = idx - 16384, n = l >> 7, k = l & 127;
    wts[idx] = f2bf(aggW[k * 128 + n]);
  } else if (idx < 57344) {
    int l = idx - 32768, n = l / 192, k = l - n * 192;
    wts[idx] = f2bf(msgW1[k * 128 + n]);
  } else if (idx < 73728) {
    int l = idx - 57344, n = l >> 7, k = l & 127;
    wts[idx] = f2bf(msgW2[k * 128 + n]);
  } else if (idx < 114688) {
    int l = idx - 73728, n = l / 320, k = l - n * 320;
    wts[idx] = f2bf(gateW1[k * 128 + n]);
  } else if (idx < 147456) {
    int l = idx - 114688, n = l >> 7, k = l & 127;
    wts[idx] = f2bf(ffnW1[k * 256 + n]);
  } else if (idx < 180224) {
    int l = idx - 147456, n = l >> 8, k = l & 255;
    wts[idx] = f2bf(ffnW2[k * 128 + n]);
  }
}

// ---- LayerNorm over 128 cols, one wave per row, writes bf16.
__global__ __launch_bounds__(256) void ln_kernel(
    const float* __restrict__ in, const float* __restrict__ g,
    const float* __restrict__ b, unsigned short* __restrict__ outbf,
    int nrows) {
  const int wid = threadIdx.x >> 6, lane = threadIdx.x & 63;
  const int row = blockIdx.x * 4 + wid;
  if (row >= nrows) return;
  const float2 v =
      *reinterpret_cast<const float2*>(in + (size_t)row * 128 + lane * 2);
  float s = v.x + v.y;
#pragma unroll
  for (int m = 32; m >= 1; m >>= 1) s += __shfl_xor(s, m);
  const float mean = s * 0.0078125f;
  const float dx = v.x - mean, dy = v.y - mean;
  float vs = dx * dx + dy * dy;
#pragma unroll
  for (int m = 32; m >= 1; m >>= 1) vs += __shfl_xor(vs, m);
  const float rs = rsqrtf(vs * 0.0078125f + 1e-5f);
  const float y0 = dx * rs * g[lane * 2] + b[lane * 2];
  const float y1 = dy * rs * g[lane * 2 + 1] + b[lane * 2 + 1];
  reinterpret_cast<unsigned int*>(outbf)[(size_t)row * 64 + lane] =
      (unsigned int)f2bf(y0) | ((unsigned int)f2bf(y1) << 16);
}

// ---- edge kernel: 64 edges/block, 4 waves x 16 edges, N=128 per wave.
__global__ __launch_bounds__(256) void edge_kernel(
    const float* __restrict__ emb, const float* __restrict__ tw,
    const float* __restrict__ mns, const int* __restrict__ esrc,
    const int* __restrict__ edst, const unsigned short* __restrict__ hbf,
    const unsigned short* __restrict__ wts, const float* __restrict__ msgb1,
    const float* __restrict__ msgb2, const float* __restrict__ gateb1,
    const float* __restrict__ gateW2, const float* __restrict__ gateb2v,
    float* __restrict__ erout, float* __restrict__ agg,
    float* __restrict__ deg) {
  __shared__ unsigned short t1s[4][16 * 136];  // pitch 136 -> 2-way-free banks
  const int wid = threadIdx.x >> 6;
  const int lane = threadIdx.x & 63;
  const int q = lane >> 4;
  const int r16 = lane & 15;
  const int koff = q * 8;
  const int e0 = blockIdx.x * 64 + wid * 16;
  const int e = e0 + r16;
  const int si = esrc[e];
  const int di = edst[e];
  const float sc = tw[e] * 0.5f * (mns[si] + mns[di]);

  const unsigned short* gateW1T = wts + 73728;  // [128][320]
  const unsigned short* msgW1T = wts + 32768;   // [128][192]
  const unsigned short* msgW2T = wts + 57344;   // [128][128]

  // ---- gate GEMM, K=320, A = [hd | hs | emb]
  f32x4 accg[8];
#pragma unroll
  for (int nt = 0; nt < 8; nt++) accg[nt] = (f32x4){0.f, 0.f, 0.f, 0.f};
#pragma unroll
  for (int s = 0; s < 10; s++) {
    const int k0 = s * 32 + koff;
    short8 a;
    if (s < 4)
      a = ld8(hbf + (size_t)di * 128 + k0);
    else if (s < 8)
      a = ld8(hbf + (size_t)si * 128 + (k0 - 128));
    else
      a = cvt8(emb + (size_t)e * 64 + (k0 - 256));
#pragma unroll
    for (int nt = 0; nt < 8; nt++) {
      const short8 b = ld8(gateW1T + (nt * 16 + r16) * 320 + k0);
      accg[nt] = MFMA(a, b, accg[nt]);
    }
  }
  // gate scalar = sigmoid(gelu(accg + b1) . w2 + b2); fold tw & node scales in.
  float p0 = 0.f, p1 = 0.f, p2 = 0.f, p3 = 0.f;
#pragma unroll
  for (int nt = 0; nt < 8; nt++) {
    const int c = r16 + 16 * nt;
    const float b1 = gateb1[c];
    const float w2 = gateW2[c];
    p0 += geluf(accg[nt][0] + b1) * w2;
    p1 += geluf(accg[nt][1] + b1) * w2;
    p2 += geluf(accg[nt][2] + b1) * w2;
    p3 += geluf(accg[nt][3] + b1) * w2;
  }
#pragma unroll
  for (int m = 1; m < 16; m <<= 1) {
    p0 += __shfl_xor(p0, m);
    p1 += __shfl_xor(p1, m);
    p2 += __shfl_xor(p2, m);
    p3 += __shfl_xor(p3, m);
  }
  const float gb2 = gateb2v[0];
  float G[4];
  {
    const float ps[4] = {p0, p1, p2, p3};
#pragma unroll
    for (int j = 0; j < 4; j++) {
      const float sce = __shfl(sc, q * 4 + j);
      G[j] = sce / (1.f + expf(-(ps[j] + gb2)));
    }
  }

  // ---- msg GEMM1, K=192, A = [hs | emb]
  f32x4 acc1[8];
#pragma unroll
  for (int nt = 0; nt < 8; nt++) acc1[nt] = (f32x4){0.f, 0.f, 0.f, 0.f};
#pragma unroll
  for (int s = 0; s < 6; s++) {
    const int k0 = s * 32 + koff;
    short8 a;
    if (s < 4)
      a = ld8(hbf + (size_t)si * 128 + k0);
    else
      a = cvt8(emb + (size_t)e * 64 + (k0 - 128));
#pragma unroll
    for (int nt = 0; nt < 8; nt++) {
      const short8 b = ld8(msgW1T + (nt * 16 + r16) * 192 + k0);
      acc1[nt] = MFMA(a, b, acc1[nt]);
    }
  }
  // t1 = gelu(acc1 + b1) -> LDS bf16 (per-wave tile, 16 rows x 128 cols)
  unsigned short* t1w = t1s[wid];
#pragma unroll
  for (int nt = 0; nt < 8; nt++) {
    const int c = r16 + 16 * nt;
    const float b1 = msgb1[c];
#pragma unroll
    for (int j = 0; j < 4; j++)
      t1w[(q * 4 + j) * 136 + c] = f2bf(geluf(acc1[nt][j] + b1));
  }
  __syncthreads();

  // ---- msg GEMM2, K=128, A = t1 (LDS)
  f32x4 acc2[8];
#pragma unroll
  for (int nt = 0; nt < 8; nt++) acc2[nt] = (f32x4){0.f, 0.f, 0.f, 0.f};
#pragma unroll
  for (int s = 0; s < 4; s++) {
    const int k0 = s * 32 + koff;
    const short8 a = *reinterpret_cast<const short8*>(t1w + r16 * 136 + k0);
#pragma unroll
    for (int nt = 0; nt < 8; nt++) {
      const short8 b = ld8(msgW2T + (nt * 16 + r16) * 128 + k0);
      acc2[nt] = MFMA(a, b, acc2[nt]);
    }
  }

  // ---- epilogue: edge_repr write + agg atomics
#pragma unroll
  for (int j = 0; j < 4; j++) {
    const int rr = q * 4 + j;
    const int ee = e0 + rr;
    const int dd = __shfl(di, rr);
    const float g = G[j];
#pragma unroll
    for (int nt = 0; nt < 8; nt++) {
      const int c = r16 + 16 * nt;
      const float v = g * (acc2[nt][j] + msgb2[c]);
      erout[(size_t)ee * 128 + c] = v;
      atomicAdd(&agg[(size_t)dd * 128 + c], v);
    }
  }
  if (lane < 16) atomicAdd(&deg[di], 1.0f);
}

// ---- node update: out1 = x + h@selfW + selfb + (agg/max(deg,1))@aggW + aggb
__global__ __launch_bounds__(256) void node1_kernel(
    const float* __restrict__ x, const unsigned short* __restrict__ hbf,
    const float* __restrict__ agg, const float* __restrict__ deg,
    const unsigned short* __restrict__ wts, const float* __restrict__ selfb,
    const float* __restrict__ aggb, float* __restrict__ out1) {
  const int wid = threadIdx.x >> 6, lane = threadIdx.x & 63;
  const int q = lane >> 4, r16 = lane & 15, koff = q * 8;
  const int r0 = blockIdx.x * 64 + wid * 16;
  const int row = min(r0 + r16, NN - 1);
  const float inv = 1.0f / fmaxf(deg[row], 1.0f);
  const unsigned short* selfWT = wts;
  const unsigned short* aggWT = wts + 16384;
  f32x4 acc[8];
#pragma unroll
  for (int nt = 0; nt < 8; nt++) acc[nt] = (f32x4){0.f, 0.f, 0.f, 0.f};
#pragma unroll
  for (int s = 0; s < 4; s++) {
    const int k0 = s * 32 + koff;
    const short8 a1 = ld8(hbf + (size_t)row * 128 + k0);
    const float* ap = agg + (size_t)row * 128 + k0;
    const f32x4 f0 = *reinterpret_cast<const f32x4*>(ap);
    const f32x4 f1 = *reinterpret_cast<const f32x4*>(ap + 4);
    short8 a2;
    a2[0] = (short)f2bf(f0[0] * inv); a2[1] = (short)f2bf(f0[1] * inv);
    a2[2] = (short)f2bf(f0[2] * inv); a2[3] = (short)f2bf(f0[3] * inv);
    a2[4] = (short)f2bf(f1[0] * inv); a2[5] = (short)f2bf(f1[1] * inv);
    a2[6] = (short)f2bf(f1[2] * inv); a2[7] = (short)f2bf(f1[3] * inv);
#pragma unroll
    for (int nt = 0; nt < 8; nt++) {
      acc[nt] = MFMA(a1, ld8(selfWT + (nt * 16 + r16) * 128 + k0), acc[nt]);
      acc[nt] = MFMA(a2, ld8(aggWT + (nt * 16 + r16) * 128 + k0), acc[nt]);
    }
  }
#pragma unroll
  for (int j = 0; j < 4; j++) {
    const int gr = r0 + q * 4 + j;
    if (gr < NN) {
#pragma unroll
      for (int nt = 0; nt < 8; nt++) {
        const int c = r16 + 16 * nt;
        out1[(size_t)gr * 128 + c] =
            x[(size_t)gr * 128 + c] + acc[nt][j] + selfb[c] + aggb[c];
      }
    }
  }
}

// ---- FFN: out = out1 + gelu(h2@W1+b1)@W2 + b2
__global__ __launch_bounds__(256) void ffn_kernel(
    const float* __restrict__ out1, const unsigned short* __restrict__ h2bf,
    const unsigned short* __restrict__ wts, const float* __restrict__ b1,
    const float* __restrict__ b2, float* __restrict__ outp) {
  __shared__ unsigned short ts[4][16 * 264];  // pitch 264 -> 2-way-free banks
  const int wid = threadIdx.x >> 6, lane = threadIdx.x & 63;
  const int q = lane >> 4, r16 = lane & 15, koff = q * 8;
  const int r0 = blockIdx.x * 64 + wid * 16;
  const int row = min(r0 + r16, NN - 1);
  const unsigned short* W1T = wts + 114688;  // [256][128]
  const unsigned short* W2T = wts + 147456;  // [128][256]
  f32x4 acc1[16];
#pragma unroll
  for (int nt = 0; nt < 16; nt++) acc1[nt] = (f32x4){0.f, 0.f, 0.f, 0.f};
#pragma unroll
  for (int s = 0; s < 4; s++) {
    const int k0 = s * 32 + koff;
    const short8 a = ld8(h2bf + (size_t)row * 128 + k0);
#pragma unroll
    for (int nt = 0; nt < 16; nt++)
      acc1[nt] = MFMA(a, ld8(W1T + (nt * 16 + r16) * 128 + k0), acc1[nt]);
  }
  unsigned short* tw_ = ts[wid];
#pragma unroll
  for (int nt = 0; nt < 16; nt++) {
    const int c = r16 + 16 * nt;
    const float bb = b1[c];
#pragma unroll
    for (int j = 0; j < 4; j++)
      tw_[(q * 4 + j) * 264 + c] = f2bf(geluf(acc1[nt][j] + bb));
  }
  __syncthreads();
  f32x4 acc2[8];
#pragma unroll
  for (int nt = 0; nt < 8; nt++) acc2[nt] = (f32x4){0.f, 0.f, 0.f, 0.f};
#pragma unroll
  for (int s = 0; s < 8; s++) {
    const int k0 = s * 32 + koff;
    const short8 a = *reinterpret_cast<const short8*>(tw_ + r16 * 264 + k0);
#pragma unroll
    for (int nt = 0; nt < 8; nt++)
      acc2[nt] = MFMA(a, ld8(W2T + (nt * 16 + r16) * 256 + k0), acc2[nt]);
  }
#pragma unroll
  for (int j = 0; j < 4; j++) {
    const int gr = r0 + q * 4 + j;
    if (gr < NN) {
#pragma unroll
      for (int nt = 0; nt < 8; nt++) {
        const int c = r16 + 16 * nt;
        outp[(size_t)gr * 128 + c] =
            out1[(size_t)gr * 128 + c] + acc2[nt][j] + b2[c];
      }
    }
  }
}

extern "C" void kernel_launch(void* const* d_in, const int* in_sizes, int n_in,
                              void* d_out, int out_size, void* d_ws,
                              size_t ws_size, hipStream_t stream) {
  (void)in_sizes; (void)n_in; (void)out_size; (void)ws_size;
  const float* x = (const float*)d_in[0];
  const float* emb = (const float*)d_in[1];
  const float* tw = (const float*)d_in[2];
  const float* mns = (const float*)d_in[3];
  const float* ln1g = (const float*)d_in[4];
  const float* ln1b = (const float*)d_in[5];
  const float* ln2g = (const float*)d_in[6];
  const float* ln2b = (const float*)d_in[7];
  const float* selfW = (const float*)d_in[8];
  const float* selfb = (const float*)d_in[9];
  const float* msgW1 = (const float*)d_in[10];
  const float* msgb1 = (const float*)d_in[11];
  const float* msgW2 = (const float*)d_in[12];
  const float* msgb2 = (const float*)d_in[13];
  const float* gateW1 = (const float*)d_in[14];
  const float* gateb1 = (const float*)d_in[15];
  const float* gateW2 = (const float*)d_in[16];
  const float* gateb2 = (const float*)d_in[17];
  const float* aggW = (const float*)d_in[18];
  const float* aggb = (const float*)d_in[19];
  const float* ffnW1 = (const float*)d_in[20];
  const float* ffnb1 = (const float*)d_in[21];
  const float* ffnW2 = (const float*)d_in[22];
  const float* ffnb2 = (const float*)d_in[23];
  const int* esrc = (const int*)d_in[24];
  const int* edst = (const int*)d_in[25];

  // workspace layout (bytes, all 256-aligned):
  // hbf 0..12.8M | h2bf 12.8M..25.6M | agg 25.6M..51.2M | deg 51.2M..+200K
  // | out1 51,400,192..+25.6M | wts 77,000,192..+360,448   (~77.4 MB total)
  char* ws = (char*)d_ws;
  unsigned short* hbf = (unsigned short*)(ws);
  unsigned short* h2bf = (unsigned short*)(ws + 12800000);
  float* agg = (float*)(ws + 25600000);
  float* deg = (float*)(ws + 51200000);
  float* out1 = (float*)(ws + 51400192);
  unsigned short* wts = (unsigned short*)(ws + 77000192);

  float* out_nodes = (float*)d_out;
  float* out_edges = out_nodes + (size_t)NN * 128;

  prep_kernel<<<704, 256, 0, stream>>>(selfW, msgW1, msgW2, gateW1, aggW,
                                       ffnW1, ffnW2, wts);
  ln_kernel<<<12500, 256, 0, stream>>>(x, ln1g, ln1b, hbf, NN);
  hipMemsetAsync(agg, 0, 25600000 + 200192, stream);
  edge_kernel<<<12500, 256, 0, stream>>>(emb, tw, mns, esrc, edst, hbf, wts,
                                         msgb1, msgb2, gateb1, gateW2, gateb2,
                                         out_edges, agg, deg);
  node1_kernel<<<782, 256, 0, stream>>>(x, hbf, agg, deg, wts, selfb, aggb,
                                        out1);
  ln_kernel<<<12500, 256, 0, stream>>>(out1, ln2g, ln2b, h2bf, NN);
  ffn_kernel<<<782, 256, 0, stream>>>(out1, h2bf, wts, ffnb1, ffnb2,
                                      out_nodes);
}

// Round 2
// 1043.195 us; speedup vs baseline: 1.4115x; 1.4115x over previous
//
#include <hip/hip_runtime.h>

// TRGTMeanRelationBlock: graph message-passing block on MI355X (gfx950).
// Pipeline: prep(weights->bf16 W^T) ; ln1 ; memset(agg,deg) ; edge ; node1 ; ln2 ; ffn
// All heavy GEMMs via v_mfma_f32_16x16x32_bf16.
// Fragment layouts: A/B lane l -> (row/col = l&15, 8 contiguous k at (l>>4)*8).
//                   C/D lane l -> col = l&15, row = (l>>4)*4 + reg_idx.
// Edge kernel: 64 edges/block staged in LDS (XOR-swizzled); 4 waves split N
// (each wave M=64 x N=32) so weights stream once per block, not per wave.

typedef __attribute__((ext_vector_type(8))) short short8;
typedef __attribute__((ext_vector_type(4))) float f32x4;

#define NN 50000
#define NEDGE 800000

#define MFMA(a, b, c) __builtin_amdgcn_mfma_f32_16x16x32_bf16(a, b, c, 0, 0, 0)

__device__ __forceinline__ unsigned short f2bf(float f) {
  unsigned int u = __float_as_uint(f);
  u += 0x7fffu + ((u >> 16) & 1u);   // round-to-nearest-even
  return (unsigned short)(u >> 16);
}
__device__ __forceinline__ float geluf(float x) {
  return 0.5f * x * (1.0f + erff(x * 0.70710678118654752f));
}
__device__ __forceinline__ short8 ld8(const unsigned short* p) {
  return *reinterpret_cast<const short8*>(p);
}

// byte-offset swizzles: spread 16 rows across 16 distinct 16B slots.
__device__ __forceinline__ int swz256(int row, int byteoff) {  // 256 B rows
  return row * 256 + (byteoff ^ ((row & 15) << 4));
}
__device__ __forceinline__ int swz128(int row, int byteoff) {  // 128 B rows
  return row * 128 + (byteoff ^ ((row & 7) << 4));
}

// ---- weight prep: transpose + f32->bf16. WT[n][k] = W[k][n].
// ws ushort offsets: selfWT 0 (16384) | aggWT 16384 (16384) | msgW1T 32768 (24576,K=192)
// | msgW2T 57344 (16384) | gateW1T 73728 (40960,K=320) | ffnW1T 114688 (32768,K=128,N=256)
// | ffnW2T 147456 (32768,K=256,N=128)  -- total 180224 ushorts.
__global__ __launch_bounds__(256) void prep_kernel(
    const float* __restrict__ selfW, const float* __restrict__ msgW1,
    const float* __restrict__ msgW2, const float* __restrict__ gateW1,
    const float* __restrict__ aggW, const float* __restrict__ ffnW1,
    const float* __restrict__ ffnW2, unsigned short* __restrict__ wts) {
  const int idx = blockIdx.x * 256 + threadIdx.x;
  if (idx < 16384) {
    int n = idx >> 7, k = idx & 127;
    wts[idx] = f2bf(selfW[k * 128 + n]);
  } else if (idx < 32768) {
    int l = idx - 16384, n = l >> 7, k = l & 127;
    wts[idx] = f2bf(aggW[k * 128 + n]);
  } else if (idx < 57344) {
    int l = idx - 32768, n = l / 192, k = l - n * 192;
    wts[idx] = f2bf(msgW1[k * 128 + n]);
  } else if (idx < 73728) {
    int l = idx - 57344, n = l >> 7, k = l & 127;
    wts[idx] = f2bf(msgW2[k * 128 + n]);
  } else if (idx < 114688) {
    int l = idx - 73728, n = l / 320, k = l - n * 320;
    wts[idx] = f2bf(gateW1[k * 128 + n]);
  } else if (idx < 147456) {
    int l = idx - 114688, n = l >> 7, k = l & 127;
    wts[idx] = f2bf(ffnW1[k * 256 + n]);
  } else if (idx < 180224) {
    int l = idx - 147456, n = l >> 8, k = l & 255;
    wts[idx] = f2bf(ffnW2[k * 128 + n]);
  }
}

// ---- LayerNorm over 128 cols, one wave per row, writes bf16.
__global__ __launch_bounds__(256) void ln_kernel(
    const float* __restrict__ in, const float* __restrict__ g,
    const float* __restrict__ b, unsigned short* __restrict__ outbf,
    int nrows) {
  const int wid = threadIdx.x >> 6, lane = threadIdx.x & 63;
  const int row = blockIdx.x * 4 + wid;
  if (row >= nrows) return;
  const float2 v =
      *reinterpret_cast<const float2*>(in + (size_t)row * 128 + lane * 2);
  float s = v.x + v.y;
#pragma unroll
  for (int m = 32; m >= 1; m >>= 1) s += __shfl_xor(s, m);
  const float mean = s * 0.0078125f;
  const float dx = v.x - mean, dy = v.y - mean;
  float vs = dx * dx + dy * dy;
#pragma unroll
  for (int m = 32; m >= 1; m >>= 1) vs += __shfl_xor(vs, m);
  const float rs = rsqrtf(vs * 0.0078125f + 1e-5f);
  const float y0 = dx * rs * g[lane * 2] + b[lane * 2];
  const float y1 = dy * rs * g[lane * 2 + 1] + b[lane * 2 + 1];
  reinterpret_cast<unsigned int*>(outbf)[(size_t)row * 64 + lane] =
      (unsigned int)f2bf(y0) | ((unsigned int)f2bf(y1) << 16);
}

// ---- edge kernel: 64 edges/block; LDS-staged A; 4 waves x (M=64, N=32).
__global__ __launch_bounds__(256) void edge_kernel(
    const float* __restrict__ emb, const float* __restrict__ tw,
    const float* __restrict__ mns, const int* __restrict__ esrc,
    const int* __restrict__ edst, const unsigned short* __restrict__ hbf,
    const unsigned short* __restrict__ wts, const float* __restrict__ msgb1,
    const float* __restrict__ msgb2, const float* __restrict__ gateb1,
    const float* __restrict__ gateW2, const float* __restrict__ gateb2v,
    float* __restrict__ erout, float* __restrict__ agg,
    float* __restrict__ deg) {
  __shared__ unsigned short hs_s[64 * 128];   // 16 KB, swizzled (256B rows)
  __shared__ unsigned short hd_s[64 * 128];   // 16 KB; reused as t1 later
  __shared__ unsigned short emb_s[64 * 64];   // 8 KB, swizzled (128B rows)
  __shared__ float p_s[4][64];                // gate partials per wave
  __shared__ float G_s[64];
  __shared__ float sc_s[64];
  __shared__ int di_s[64];

  const int tid = threadIdx.x;
  const int wid = tid >> 6;
  const int lane = tid & 63;
  const int q = lane >> 4;
  const int r16 = lane & 15;
  const int koff = q * 8;
  const int e0 = blockIdx.x * 64;

  const unsigned short* gateW1T = wts + 73728;  // [128][320]
  const unsigned short* msgW1T = wts + 32768;   // [128][192]
  const unsigned short* msgW2T = wts + 57344;   // [128][128]

  // ---- stage hs, hd, emb(bf16) into LDS; per-edge scalars
  {
    const int row = tid >> 2;  // 0..63
    const int c4 = tid & 3;    // 0..3
    const int e = e0 + row;
    const int si = esrc[e];
    const int di = edst[e];
    if (c4 == 0) {
      di_s[row] = di;
      sc_s[row] = tw[e] * 0.5f * (mns[si] + mns[di]);
    }
#pragma unroll
    for (int i = 0; i < 4; i++) {
      const int c = c4 + 4 * i;  // 16B chunk id, 0..15
      const short8 vs = ld8(hbf + (size_t)si * 128 + c * 8);
      const short8 vd = ld8(hbf + (size_t)di * 128 + c * 8);
      *reinterpret_cast<short8*>((char*)hs_s + swz256(row, c * 16)) = vs;
      *reinterpret_cast<short8*>((char*)hd_s + swz256(row, c * 16)) = vd;
    }
#pragma unroll
    for (int i = 0; i < 4; i++) {
      const f32x4 v =
          *reinterpret_cast<const f32x4*>(emb + (size_t)e * 64 + c4 * 16 + i * 4);
      unsigned int lo = (unsigned int)f2bf(v[0]) | ((unsigned int)f2bf(v[1]) << 16);
      unsigned int hi = (unsigned int)f2bf(v[2]) | ((unsigned int)f2bf(v[3]) << 16);
      unsigned int* p =
          reinterpret_cast<unsigned int*>((char*)emb_s + swz128(row, c4 * 32 + i * 8));
      p[0] = lo;
      p[1] = hi;
    }
  }
  __syncthreads();

  // ---- gate GEMM: S = [hd|hs|emb] @ gateW1, K=320. Wave covers N cols
  // nt in {2*wid, 2*wid+1}; M=64 (4 row tiles).
  f32x4 accg[4][2];
#pragma unroll
  for (int m = 0; m < 4; m++)
#pragma unroll
    for (int i = 0; i < 2; i++) accg[m][i] = (f32x4){0.f, 0.f, 0.f, 0.f};
#pragma unroll
  for (int s = 0; s < 10; s++) {
    const int k0 = s * 32 + koff;  // 0..319
    short8 a[4];
#pragma unroll
    for (int m = 0; m < 4; m++) {
      const int r = m * 16 + r16;
      if (s < 4)
        a[m] = *reinterpret_cast<const short8*>((char*)hd_s + swz256(r, k0 * 2));
      else if (s < 8)
        a[m] = *reinterpret_cast<const short8*>((char*)hs_s + swz256(r, (k0 - 128) * 2));
      else
        a[m] = *reinterpret_cast<const short8*>((char*)emb_s + swz128(r, (k0 - 256) * 2));
    }
#pragma unroll
    for (int i = 0; i < 2; i++) {
      const int nt = 2 * wid + i;
      const short8 b = ld8(gateW1T + (nt * 16 + r16) * 320 + k0);
#pragma unroll
      for (int m = 0; m < 4; m++) accg[m][i] = MFMA(a[m], b, accg[m][i]);
    }
  }

  // ---- msg GEMM1: [hs|emb] @ msgW1, K=192 (before t1 overwrites hd).
  f32x4 acc1[4][2];
#pragma unroll
  for (int m = 0; m < 4; m++)
#pragma unroll
    for (int i = 0; i < 2; i++) acc1[m][i] = (f32x4){0.f, 0.f, 0.f, 0.f};
#pragma unroll
  for (int s = 0; s < 6; s++) {
    const int k0 = s * 32 + koff;  // 0..191
    short8 a[4];
#pragma unroll
    for (int m = 0; m < 4; m++) {
      const int r = m * 16 + r16;
      if (s < 4)
        a[m] = *reinterpret_cast<const short8*>((char*)hs_s + swz256(r, k0 * 2));
      else
        a[m] = *reinterpret_cast<const short8*>((char*)emb_s + swz128(r, (k0 - 128) * 2));
    }
#pragma unroll
    for (int i = 0; i < 2; i++) {
      const int nt = 2 * wid + i;
      const short8 b = ld8(msgW1T + (nt * 16 + r16) * 192 + k0);
#pragma unroll
      for (int m = 0; m < 4; m++) acc1[m][i] = MFMA(a[m], b, acc1[m][i]);
    }
  }

  // ---- gate partial: p[row] += sum over this wave's 32 cols of gelu(S+b1)*w2
#pragma unroll
  for (int m = 0; m < 4; m++) {
#pragma unroll
    for (int j = 0; j < 4; j++) {
      float v = 0.f;
#pragma unroll
      for (int i = 0; i < 2; i++) {
        const int c = (2 * wid + i) * 16 + r16;
        v += geluf(accg[m][i][j] + gateb1[c]) * gateW2[c];
      }
      v += __shfl_xor(v, 1);
      v += __shfl_xor(v, 2);
      v += __shfl_xor(v, 4);
      v += __shfl_xor(v, 8);
      if (r16 == 0) p_s[wid][m * 16 + q * 4 + j] = v;
    }
  }
  __syncthreads();  // p_s ready; all hd reads done

  // ---- G (gate scalar with tw & node scales folded), one thread per edge
  if (tid < 64) {
    const float p = p_s[0][tid] + p_s[1][tid] + p_s[2][tid] + p_s[3][tid];
    G_s[tid] = sc_s[tid] / (1.f + expf(-(p + gateb2v[0])));
  }

  // ---- t1 = gelu(msg1 + b1) -> LDS (overwrites hd_s), swizzled bf16
#pragma unroll
  for (int m = 0; m < 4; m++) {
#pragma unroll
    for (int i = 0; i < 2; i++) {
      const int c = (2 * wid + i) * 16 + r16;
      const float b1 = msgb1[c];
#pragma unroll
      for (int j = 0; j < 4; j++) {
        const int r = m * 16 + q * 4 + j;
        *reinterpret_cast<unsigned short*>((char*)hd_s + swz256(r, c * 2)) =
            f2bf(geluf(acc1[m][i][j] + b1));
      }
    }
  }
  __syncthreads();  // t1 + G ready

  // ---- msg GEMM2: t1 @ msgW2, K=128
  f32x4 acc2[4][2];
#pragma unroll
  for (int m = 0; m < 4; m++)
#pragma unroll
    for (int i = 0; i < 2; i++) acc2[m][i] = (f32x4){0.f, 0.f, 0.f, 0.f};
#pragma unroll
  for (int s = 0; s < 4; s++) {
    const int k0 = s * 32 + koff;
    short8 a[4];
#pragma unroll
    for (int m = 0; m < 4; m++)
      a[m] = *reinterpret_cast<const short8*>(
          (char*)hd_s + swz256(m * 16 + r16, k0 * 2));
#pragma unroll
    for (int i = 0; i < 2; i++) {
      const int nt = 2 * wid + i;
      const short8 b = ld8(msgW2T + (nt * 16 + r16) * 128 + k0);
#pragma unroll
      for (int m = 0; m < 4; m++) acc2[m][i] = MFMA(a[m], b, acc2[m][i]);
    }
  }

  // ---- epilogue: edge_repr write + agg atomics (wave's 32-col slice)
#pragma unroll
  for (int m = 0; m < 4; m++) {
#pragma unroll
    for (int j = 0; j < 4; j++) {
      const int rr = m * 16 + q * 4 + j;
      const float g = G_s[rr];
      const int dd = di_s[rr];
      const int ee = e0 + rr;
#pragma unroll
      for (int i = 0; i < 2; i++) {
        const int c = (2 * wid + i) * 16 + r16;
        const float v = g * (acc2[m][i][j] + msgb2[c]);
        erout[(size_t)ee * 128 + c] = v;
        atomicAdd(&agg[(size_t)dd * 128 + c], v);
      }
    }
  }
  if (tid < 64) atomicAdd(&deg[di_s[tid]], 1.0f);
}

// ---- node update: out1 = x + h@selfW + selfb + (agg/max(deg,1))@aggW + aggb
__global__ __launch_bounds__(256) void node1_kernel(
    const float* __restrict__ x, const unsigned short* __restrict__ hbf,
    const float* __restrict__ agg, const float* __restrict__ deg,
    const unsigned short* __restrict__ wts, const float* __restrict__ selfb,
    const float* __restrict__ aggb, float* __restrict__ out1) {
  const int wid = threadIdx.x >> 6, lane = threadIdx.x & 63;
  const int q = lane >> 4, r16 = lane & 15, koff = q * 8;
  const int r0 = blockIdx.x * 64 + wid * 16;
  const int row = min(r0 + r16, NN - 1);
  const float inv = 1.0f / fmaxf(deg[row], 1.0f);
  const unsigned short* selfWT = wts;
  const unsigned short* aggWT = wts + 16384;
  f32x4 acc[8];
#pragma unroll
  for (int nt = 0; nt < 8; nt++) acc[nt] = (f32x4){0.f, 0.f, 0.f, 0.f};
#pragma unroll
  for (int s = 0; s < 4; s++) {
    const int k0 = s * 32 + koff;
    const short8 a1 = ld8(hbf + (size_t)row * 128 + k0);
    const float* ap = agg + (size_t)row * 128 + k0;
    const f32x4 f0 = *reinterpret_cast<const f32x4*>(ap);
    const f32x4 f1 = *reinterpret_cast<const f32x4*>(ap + 4);
    short8 a2;
    a2[0] = (short)f2bf(f0[0] * inv); a2[1] = (short)f2bf(f0[1] * inv);
    a2[2] = (short)f2bf(f0[2] * inv); a2[3] = (short)f2bf(f0[3] * inv);
    a2[4] = (short)f2bf(f1[0] * inv); a2[5] = (short)f2bf(f1[1] * inv);
    a2[6] = (short)f2bf(f1[2] * inv); a2[7] = (short)f2bf(f1[3] * inv);
#pragma unroll
    for (int nt = 0; nt < 8; nt++) {
      acc[nt] = MFMA(a1, ld8(selfWT + (nt * 16 + r16) * 128 + k0), acc[nt]);
      acc[nt] = MFMA(a2, ld8(aggWT + (nt * 16 + r16) * 128 + k0), acc[nt]);
    }
  }
#pragma unroll
  for (int j = 0; j < 4; j++) {
    const int gr = r0 + q * 4 + j;
    if (gr < NN) {
#pragma unroll
      for (int nt = 0; nt < 8; nt++) {
        const int c = r16 + 16 * nt;
        out1[(size_t)gr * 128 + c] =
            x[(size_t)gr * 128 + c] + acc[nt][j] + selfb[c] + aggb[c];
      }
    }
  }
}

// ---- FFN: out = out1 + gelu(h2@W1+b1)@W2 + b2
__global__ __launch_bounds__(256) void ffn_kernel(
    const float* __restrict__ out1, const unsigned short* __restrict__ h2bf,
    const unsigned short* __restrict__ wts, const float* __restrict__ b1,
    const float* __restrict__ b2, float* __restrict__ outp) {
  __shared__ unsigned short ts[4][16 * 264];  // pitch 264 -> 2-way-free banks
  const int wid = threadIdx.x >> 6, lane = threadIdx.x & 63;
  const int q = lane >> 4, r16 = lane & 15, koff = q * 8;
  const int r0 = blockIdx.x * 64 + wid * 16;
  const int row = min(r0 + r16, NN - 1);
  const unsigned short* W1T = wts + 114688;  // [256][128]
  const unsigned short* W2T = wts + 147456;  // [128][256]
  f32x4 acc1[16];
#pragma unroll
  for (int nt = 0; nt < 16; nt++) acc1[nt] = (f32x4){0.f, 0.f, 0.f, 0.f};
#pragma unroll
  for (int s = 0; s < 4; s++) {
    const int k0 = s * 32 + koff;
    const short8 a = ld8(h2bf + (size_t)row * 128 + k0);
#pragma unroll
    for (int nt = 0; nt < 16; nt++)
      acc1[nt] = MFMA(a, ld8(W1T + (nt * 16 + r16) * 128 + k0), acc1[nt]);
  }
  unsigned short* tw_ = ts[wid];
#pragma unroll
  for (int nt = 0; nt < 16; nt++) {
    const int c = r16 + 16 * nt;
    const float bb = b1[c];
#pragma unroll
    for (int j = 0; j < 4; j++)
      tw_[(q * 4 + j) * 264 + c] = f2bf(geluf(acc1[nt][j] + bb));
  }
  __syncthreads();
  f32x4 acc2[8];
#pragma unroll
  for (int nt = 0; nt < 8; nt++) acc2[nt] = (f32x4){0.f, 0.f, 0.f, 0.f};
#pragma unroll
  for (int s = 0; s < 8; s++) {
    const int k0 = s * 32 + koff;
    const short8 a = *reinterpret_cast<const short8*>(tw_ + r16 * 264 + k0);
#pragma unroll
    for (int nt = 0; nt < 8; nt++)
      acc2[nt] = MFMA(a, ld8(W2T + (nt * 16 + r16) * 256 + k0), acc2[nt]);
  }
#pragma unroll
  for (int j = 0; j < 4; j++) {
    const int gr = r0 + q * 4 + j;
    if (gr < NN) {
#pragma unroll
      for (int nt = 0; nt < 8; nt++) {
        const int c = r16 + 16 * nt;
        outp[(size_t)gr * 128 + c] =
            out1[(size_t)gr * 128 + c] + acc2[nt][j] + b2[c];
      }
    }
  }
}

extern "C" void kernel_launch(void* const* d_in, const int* in_sizes, int n_in,
                              void* d_out, int out_size, void* d_ws,
                              size_t ws_size, hipStream_t stream) {
  (void)in_sizes; (void)n_in; (void)out_size; (void)ws_size;
  const float* x = (const float*)d_in[0];
  const float* emb = (const float*)d_in[1];
  const float* tw = (const float*)d_in[2];
  const float* mns = (const float*)d_in[3];
  const float* ln1g = (const float*)d_in[4];
  const float* ln1b = (const float*)d_in[5];
  const float* ln2g = (const float*)d_in[6];
  const float* ln2b = (const float*)d_in[7];
  const float* selfW = (const float*)d_in[8];
  const float* selfb = (const float*)d_in[9];
  const float* msgW1 = (const float*)d_in[10];
  const float* msgb1 = (const float*)d_in[11];
  const float* msgW2 = (const float*)d_in[12];
  const float* msgb2 = (const float*)d_in[13];
  const float* gateW1 = (const float*)d_in[14];
  const float* gateb1 = (const float*)d_in[15];
  const float* gateW2 = (const float*)d_in[16];
  const float* gateb2 = (const float*)d_in[17];
  const float* aggW = (const float*)d_in[18];
  const float* aggb = (const float*)d_in[19];
  const float* ffnW1 = (const float*)d_in[20];
  const float* ffnb1 = (const float*)d_in[21];
  const float* ffnW2 = (const float*)d_in[22];
  const float* ffnb2 = (const float*)d_in[23];
  const int* esrc = (const int*)d_in[24];
  const int* edst = (const int*)d_in[25];

  // workspace layout (bytes, all 256-aligned):
  // hbf 0..12.8M | h2bf 12.8M..25.6M | agg 25.6M..51.2M | deg 51.2M..+200K
  // | out1 51,400,192..+25.6M | wts 77,000,192..+360,448   (~77.4 MB total)
  char* ws = (char*)d_ws;
  unsigned short* hbf = (unsigned short*)(ws);
  unsigned short* h2bf = (unsigned short*)(ws + 12800000);
  float* agg = (float*)(ws + 25600000);
  float* deg = (float*)(ws + 51200000);
  float* out1 = (float*)(ws + 51400192);
  unsigned short* wts = (unsigned short*)(ws + 77000192);

  float* out_nodes = (float*)d_out;
  float* out_edges = out_nodes + (size_t)NN * 128;

  prep_kernel<<<704, 256, 0, stream>>>(selfW, msgW1, msgW2, gateW1, aggW,
                                       ffnW1, ffnW2, wts);
  ln_kernel<<<12500, 256, 0, stream>>>(x, ln1g, ln1b, hbf, NN);
  hipMemsetAsync(agg, 0, 25600000 + 200192, stream);
  edge_kernel<<<12500, 256, 0, stream>>>(emb, tw, mns, esrc, edst, hbf, wts,
                                         msgb1, msgb2, gateb1, gateW2, gateb2,
                                         out_edges, agg, deg);
  node1_kernel<<<782, 256, 0, stream>>>(x, hbf, agg, deg, wts, selfb, aggb,
                                        out1);
  ln_kernel<<<12500, 256, 0, stream>>>(out1, ln2g, ln2b, h2bf, NN);
  ffn_kernel<<<782, 256, 0, stream>>>(out1, h2bf, wts, ffnb1, ffnb2,
                                      out_nodes);
}

// Round 3
// 922.691 us; speedup vs baseline: 1.5958x; 1.1306x over previous
//
#include <hip/hip_runtime.h>

// TRGTMeanRelationBlock on MI355X (gfx950).
// Pipeline: prep ; ln1 ; memset(cnt) ; count ; scan x3 ; scatter(CSR) ;
//           edge (GEMMs, stores only) ; agg (CSR gather) ; node1 ; ln2 ; ffn
// Heavy GEMMs via v_mfma_f32_16x16x32_bf16.
// Fragment layouts: A/B lane l -> (row/col = l&15, 8 contiguous k at (l>>4)*8).
//                   C/D lane l -> col = l&15, row = (l>>4)*4 + reg_idx.
// Edge kernel: 96 edges/block, 8 waves x (M=96, N=16); A staged in LDS
// (XOR-swizzled); weights stream once per block. No atomics (CSR two-phase).

typedef __attribute__((ext_vector_type(8))) short short8;
typedef __attribute__((ext_vector_type(4))) float f32x4;

#define NN 50000
#define NEDGE 800000

#define MFMA(a, b, c) __builtin_amdgcn_mfma_f32_16x16x32_bf16(a, b, c, 0, 0, 0)

__device__ __forceinline__ unsigned short f2bf(float f) {
  unsigned int u = __float_as_uint(f);
  u += 0x7fffu + ((u >> 16) & 1u);  // round-to-nearest-even
  return (unsigned short)(u >> 16);
}
__device__ __forceinline__ float geluf(float x) {
  return 0.5f * x * (1.0f + erff(x * 0.70710678118654752f));
}
__device__ __forceinline__ short8 ld8(const unsigned short* p) {
  return *reinterpret_cast<const short8*>(p);
}
__device__ __forceinline__ int swz256(int row, int byteoff) {  // 256 B rows
  return row * 256 + (byteoff ^ ((row & 15) << 4));
}
__device__ __forceinline__ int swz128(int row, int byteoff) {  // 128 B rows
  return row * 128 + (byteoff ^ ((row & 7) << 4));
}

// ---- weight prep: transpose + f32->bf16. WT[n][k] = W[k][n].
__global__ __launch_bounds__(256) void prep_kernel(
    const float* __restrict__ selfW, const float* __restrict__ msgW1,
    const float* __restrict__ msgW2, const float* __restrict__ gateW1,
    const float* __restrict__ aggW, const float* __restrict__ ffnW1,
    const float* __restrict__ ffnW2, unsigned short* __restrict__ wts) {
  const int idx = blockIdx.x * 256 + threadIdx.x;
  if (idx < 16384) {
    int n = idx >> 7, k = idx & 127;
    wts[idx] = f2bf(selfW[k * 128 + n]);
  } else if (idx < 32768) {
    int l = idx - 16384, n = l >> 7, k = l & 127;
    wts[idx] = f2bf(aggW[k * 128 + n]);
  } else if (idx < 57344) {
    int l = idx - 32768, n = l / 192, k = l - n * 192;
    wts[idx] = f2bf(msgW1[k * 128 + n]);
  } else if (idx < 73728) {
    int l = idx - 57344, n = l >> 7, k = l & 127;
    wts[idx] = f2bf(msgW2[k * 128 + n]);
  } else if (idx < 114688) {
    int l = idx - 73728, n = l / 320, k = l - n * 320;
    wts[idx] = f2bf(gateW1[k * 128 + n]);
  } else if (idx < 147456) {
    int l = idx - 114688, n = l >> 7, k = l & 127;
    wts[idx] = f2bf(ffnW1[k * 256 + n]);
  } else if (idx < 180224) {
    int l = idx - 147456, n = l >> 8, k = l & 255;
    wts[idx] = f2bf(ffnW2[k * 128 + n]);
  }
}

// ---- LayerNorm over 128 cols, one wave per row, writes bf16.
__global__ __launch_bounds__(256) void ln_kernel(
    const float* __restrict__ in, const float* __restrict__ g,
    const float* __restrict__ b, unsigned short* __restrict__ outbf,
    int nrows) {
  const int wid = threadIdx.x >> 6, lane = threadIdx.x & 63;
  const int row = blockIdx.x * 4 + wid;
  if (row >= nrows) return;
  const float2 v =
      *reinterpret_cast<const float2*>(in + (size_t)row * 128 + lane * 2);
  float s = v.x + v.y;
#pragma unroll
  for (int m = 32; m >= 1; m >>= 1) s += __shfl_xor(s, m);
  const float mean = s * 0.0078125f;
  const float dx = v.x - mean, dy = v.y - mean;
  float vs = dx * dx + dy * dy;
#pragma unroll
  for (int m = 32; m >= 1; m >>= 1) vs += __shfl_xor(vs, m);
  const float rs = rsqrtf(vs * 0.0078125f + 1e-5f);
  const float y0 = dx * rs * g[lane * 2] + b[lane * 2];
  const float y1 = dy * rs * g[lane * 2 + 1] + b[lane * 2 + 1];
  reinterpret_cast<unsigned int*>(outbf)[(size_t)row * 64 + lane] =
      (unsigned int)f2bf(y0) | ((unsigned int)f2bf(y1) << 16);
}

// ---- CSR build ----
__global__ __launch_bounds__(256) void count_kernel(
    const int* __restrict__ edst, int* __restrict__ cnt) {
  const int e = blockIdx.x * 256 + threadIdx.x;
  atomicAdd(&cnt[edst[e]], 1);
}

// per-block sums of cnt (196 blocks x 256)
__global__ __launch_bounds__(256) void scan_sums_kernel(
    const int* __restrict__ cnt, int* __restrict__ bsum) {
  const int gi = blockIdx.x * 256 + threadIdx.x;
  int v = (gi < NN) ? cnt[gi] : 0;
#pragma unroll
  for (int m = 1; m < 64; m <<= 1) v += __shfl_xor(v, m);
  __shared__ int wsum[4];
  if ((threadIdx.x & 63) == 0) wsum[threadIdx.x >> 6] = v;
  __syncthreads();
  if (threadIdx.x == 0)
    bsum[blockIdx.x] = wsum[0] + wsum[1] + wsum[2] + wsum[3];
}

// exclusive scan of 196 block sums (1 block)
__global__ __launch_bounds__(256) void scan_offsets_kernel(
    const int* __restrict__ bsum, int* __restrict__ boff, int nb) {
  __shared__ int tmp[256];
  const int tid = threadIdx.x;
  const int v = (tid < nb) ? bsum[tid] : 0;
  tmp[tid] = v;
  __syncthreads();
#pragma unroll
  for (int d = 1; d < 256; d <<= 1) {
    const int t = (tid >= d) ? tmp[tid - d] : 0;
    __syncthreads();
    tmp[tid] += t;
    __syncthreads();
  }
  if (tid < nb) boff[tid] = tmp[tid] - v;  // exclusive
}

// final: row_start (exclusive) + cursor copy
__global__ __launch_bounds__(256) void scan_final_kernel(
    const int* __restrict__ cnt, const int* __restrict__ boff,
    int* __restrict__ row_start, int* __restrict__ cursor) {
  const int tid = threadIdx.x, lane = tid & 63, wid = tid >> 6;
  const int gi = blockIdx.x * 256 + tid;
  const int val = (gi < NN) ? cnt[gi] : 0;
  int v = val;
#pragma unroll
  for (int d = 1; d < 64; d <<= 1) {
    const int t = __shfl_up(v, d);
    if (lane >= d) v += t;
  }
  __shared__ int wsum[4];
  if (lane == 63) wsum[wid] = v;
  __syncthreads();
  int woff = 0;
  for (int w = 0; w < wid; ++w) woff += wsum[w];
  const int excl = (v - val) + woff + boff[blockIdx.x];
  if (gi < NN) {
    row_start[gi] = excl;
    cursor[gi] = excl;
  }
  if (gi == NN - 1) row_start[NN] = excl + val;
}

__global__ __launch_bounds__(256) void scatter_kernel(
    const int* __restrict__ edst, int* __restrict__ cursor,
    int* __restrict__ eidx) {
  const int e = blockIdx.x * 256 + threadIdx.x;
  const int pos = atomicAdd(&cursor[edst[e]], 1);
  eidx[pos] = e;
}

// ---- edge kernel: 96 edges/block; 8 waves x (M=96, N=16); stores only.
__global__ __launch_bounds__(512, 4) void edge_kernel(
    const float* __restrict__ emb, const float* __restrict__ tw,
    const float* __restrict__ mns, const int* __restrict__ esrc,
    const int* __restrict__ edst, const unsigned short* __restrict__ hbf,
    const unsigned short* __restrict__ wts, const float* __restrict__ msgb1,
    const float* __restrict__ msgb2, const float* __restrict__ gateb1,
    const float* __restrict__ gateW2, const float* __restrict__ gateb2v,
    float* __restrict__ erout) {
  __shared__ unsigned short hs_s[96 * 128];  // 24 KB, swizzled 256B rows
  __shared__ unsigned short hd_s[96 * 128];  // 24 KB; reused as t1
  __shared__ unsigned short emb_s[96 * 64];  // 12 KB, swizzled 128B rows
  __shared__ float p_s[8][96];               // gate partials per wave
  __shared__ float G_s[96];
  __shared__ float sc_s[96];

  const int tid = threadIdx.x;
  const int wid = tid >> 6;
  const int lane = tid & 63;
  const int q = lane >> 4;
  const int r16 = lane & 15;
  const int koff = q * 8;
  const int e0 = blockIdx.x * 96;
  const int rem = min(96, NEDGE - e0);

  const unsigned short* gateW1T = wts + 73728;  // [128][320]
  const unsigned short* msgW1T = wts + 32768;   // [128][192]
  const unsigned short* msgW2T = wts + 57344;   // [128][128]

  // ---- stage hs, hd (bf16 gather) and emb (f32->bf16) into LDS
#pragma unroll
  for (int r = 0; r < 3; r++) {
    const int idx = tid + 512 * r;  // < 1536
    const int row = idx >> 4;
    const int c = idx & 15;  // 16B chunk
    const int e = min(e0 + row, NEDGE - 1);
    const int si = esrc[e];
    const int di = edst[e];
    *reinterpret_cast<short8*>((char*)hs_s + swz256(row, c * 16)) =
        ld8(hbf + (size_t)si * 128 + c * 8);
    *reinterpret_cast<short8*>((char*)hd_s + swz256(row, c * 16)) =
        ld8(hbf + (size_t)di * 128 + c * 8);
  }
  if (tid < 384) {
    const int row = tid >> 2, c4 = tid & 3;
    const int e = min(e0 + row, NEDGE - 1);
#pragma unroll
    for (int i = 0; i < 4; i++) {
      const f32x4 v =
          *reinterpret_cast<const f32x4*>(emb + (size_t)e * 64 + c4 * 16 + i * 4);
      unsigned int* p = reinterpret_cast<unsigned int*>(
          (char*)emb_s + swz128(row, c4 * 32 + i * 8));
      p[0] = (unsigned int)f2bf(v[0]) | ((unsigned int)f2bf(v[1]) << 16);
      p[1] = (unsigned int)f2bf(v[2]) | ((unsigned int)f2bf(v[3]) << 16);
    }
  }
  if (tid < 96) {
    const int e = min(e0 + tid, NEDGE - 1);
    sc_s[tid] = tw[e] * 0.5f * (mns[esrc[e]] + mns[edst[e]]);
  }
  __syncthreads();

  const int cc = wid * 16 + r16;  // this wave's output column

  // ---- gate GEMM: [hd|hs|emb] @ gateW1, K=320; wave N-slice = cols cc
  f32x4 accg[6];
#pragma unroll
  for (int m = 0; m < 6; m++) accg[m] = (f32x4){0.f, 0.f, 0.f, 0.f};
#pragma unroll
  for (int s = 0; s < 10; s++) {
    const int k0 = s * 32 + koff;
    const short8 b = ld8(gateW1T + cc * 320 + k0);
#pragma unroll
    for (int m = 0; m < 6; m++) {
      const int r = m * 16 + r16;
      short8 a;
      if (s < 4)
        a = *reinterpret_cast<const short8*>((char*)hd_s + swz256(r, k0 * 2));
      else if (s < 8)
        a = *reinterpret_cast<const short8*>((char*)hs_s + swz256(r, (k0 - 128) * 2));
      else
        a = *reinterpret_cast<const short8*>((char*)emb_s + swz128(r, (k0 - 256) * 2));
      accg[m] = MFMA(a, b, accg[m]);
    }
  }

  // ---- msg GEMM1: [hs|emb] @ msgW1, K=192
  f32x4 acc1[6];
#pragma unroll
  for (int m = 0; m < 6; m++) acc1[m] = (f32x4){0.f, 0.f, 0.f, 0.f};
#pragma unroll
  for (int s = 0; s < 6; s++) {
    const int k0 = s * 32 + koff;
    const short8 b = ld8(msgW1T + cc * 192 + k0);
#pragma unroll
    for (int m = 0; m < 6; m++) {
      const int r = m * 16 + r16;
      short8 a;
      if (s < 4)
        a = *reinterpret_cast<const short8*>((char*)hs_s + swz256(r, k0 * 2));
      else
        a = *reinterpret_cast<const short8*>((char*)emb_s + swz128(r, (k0 - 128) * 2));
      acc1[m] = MFMA(a, b, acc1[m]);
    }
  }

  // ---- gate partials: sum over this wave's 16 cols of gelu(S+b1)*w2
  {
    const float b1 = gateb1[cc];
    const float w2 = gateW2[cc];
#pragma unroll
    for (int m = 0; m < 6; m++) {
#pragma unroll
      for (int j = 0; j < 4; j++) {
        float v = geluf(accg[m][j] + b1) * w2;
        v += __shfl_xor(v, 1);
        v += __shfl_xor(v, 2);
        v += __shfl_xor(v, 4);
        v += __shfl_xor(v, 8);
        if (r16 == 0) p_s[wid][m * 16 + q * 4 + j] = v;
      }
    }
  }
  __syncthreads();  // p_s ready; all hd_s reads done

  if (tid < 96) {
    float p = gateb2v[0];
#pragma unroll
    for (int w = 0; w < 8; w++) p += p_s[w][tid];
    G_s[tid] = sc_s[tid] / (1.f + expf(-p));
  }

  // ---- t1 = gelu(msg1 + b1) -> LDS (overwrites hd_s), swizzled bf16
  {
    const float b1 = msgb1[cc];
#pragma unroll
    for (int m = 0; m < 6; m++) {
#pragma unroll
      for (int j = 0; j < 4; j++) {
        const int r = m * 16 + q * 4 + j;
        *reinterpret_cast<unsigned short*>((char*)hd_s + swz256(r, cc * 2)) =
            f2bf(geluf(acc1[m][j] + b1));
      }
    }
  }
  __syncthreads();  // t1 + G ready

  // ---- msg GEMM2: t1 @ msgW2, K=128
  f32x4 acc2[6];
#pragma unroll
  for (int m = 0; m < 6; m++) acc2[m] = (f32x4){0.f, 0.f, 0.f, 0.f};
#pragma unroll
  for (int s = 0; s < 4; s++) {
    const int k0 = s * 32 + koff;
    const short8 b = ld8(msgW2T + cc * 128 + k0);
#pragma unroll
    for (int m = 0; m < 6; m++) {
      const short8 a = *reinterpret_cast<const short8*>(
          (char*)hd_s + swz256(m * 16 + r16, k0 * 2));
      acc2[m] = MFMA(a, b, acc2[m]);
    }
  }

  // ---- epilogue: edge_repr stores (no atomics)
  const float b2 = msgb2[cc];
#pragma unroll
  for (int m = 0; m < 6; m++) {
#pragma unroll
    for (int j = 0; j < 4; j++) {
      const int rr = m * 16 + q * 4 + j;
      if (rr < rem)
        erout[(size_t)(e0 + rr) * 128 + cc] = G_s[rr] * (acc2[m][j] + b2);
    }
  }
}

// ---- aggregate: one wave per node; agg_bf16 = (sum of edge_repr)/max(deg,1)
__global__ __launch_bounds__(256) void agg_kernel(
    const int* __restrict__ row_start, const int* __restrict__ eidx,
    const float* __restrict__ er, unsigned int* __restrict__ aggbf) {
  const int wid = threadIdx.x >> 6, lane = threadIdx.x & 63;
  const int node = blockIdx.x * 4 + wid;
  const int beg = row_start[node], end = row_start[node + 1];
  float ax = 0.f, ay = 0.f;
  for (int i = beg; i < end; ++i) {
    const int e = eidx[i];
    const float2 v =
        *reinterpret_cast<const float2*>(er + (size_t)e * 128 + lane * 2);
    ax += v.x;
    ay += v.y;
  }
  const float inv = 1.0f / fmaxf((float)(end - beg), 1.0f);
  aggbf[(size_t)node * 64 + lane] =
      (unsigned int)f2bf(ax * inv) | ((unsigned int)f2bf(ay * inv) << 16);
}

// ---- node update: out1 = x + h@selfW + selfb + aggbf@aggW + aggb
__global__ __launch_bounds__(256) void node1_kernel(
    const float* __restrict__ x, const unsigned short* __restrict__ hbf,
    const unsigned short* __restrict__ aggbf,
    const unsigned short* __restrict__ wts, const float* __restrict__ selfb,
    const float* __restrict__ aggb, float* __restrict__ out1) {
  const int wid = threadIdx.x >> 6, lane = threadIdx.x & 63;
  const int q = lane >> 4, r16 = lane & 15, koff = q * 8;
  const int r0 = blockIdx.x * 64 + wid * 16;
  const int row = min(r0 + r16, NN - 1);
  const unsigned short* selfWT = wts;
  const unsigned short* aggWT = wts + 16384;
  f32x4 acc[8];
#pragma unroll
  for (int nt = 0; nt < 8; nt++) acc[nt] = (f32x4){0.f, 0.f, 0.f, 0.f};
#pragma unroll
  for (int s = 0; s < 4; s++) {
    const int k0 = s * 32 + koff;
    const short8 a1 = ld8(hbf + (size_t)row * 128 + k0);
    const short8 a2 = ld8(aggbf + (size_t)row * 128 + k0);
#pragma unroll
    for (int nt = 0; nt < 8; nt++) {
      acc[nt] = MFMA(a1, ld8(selfWT + (nt * 16 + r16) * 128 + k0), acc[nt]);
      acc[nt] = MFMA(a2, ld8(aggWT + (nt * 16 + r16) * 128 + k0), acc[nt]);
    }
  }
#pragma unroll
  for (int j = 0; j < 4; j++) {
    const int gr = r0 + q * 4 + j;
    if (gr < NN) {
#pragma unroll
      for (int nt = 0; nt < 8; nt++) {
        const int c = r16 + 16 * nt;
        out1[(size_t)gr * 128 + c] =
            x[(size_t)gr * 128 + c] + acc[nt][j] + selfb[c] + aggb[c];
      }
    }
  }
}

// ---- FFN: out = out1 + gelu(h2@W1+b1)@W2 + b2
__global__ __launch_bounds__(256) void ffn_kernel(
    const float* __restrict__ out1, const unsigned short* __restrict__ h2bf,
    const unsigned short* __restrict__ wts, const float* __restrict__ b1,
    const float* __restrict__ b2, float* __restrict__ outp) {
  __shared__ unsigned short ts[4][16 * 264];
  const int wid = threadIdx.x >> 6, lane = threadIdx.x & 63;
  const int q = lane >> 4, r16 = lane & 15, koff = q * 8;
  const int r0 = blockIdx.x * 64 + wid * 16;
  const int row = min(r0 + r16, NN - 1);
  const unsigned short* W1T = wts + 114688;  // [256][128]
  const unsigned short* W2T = wts + 147456;  // [128][256]
  f32x4 acc1[16];
#pragma unroll
  for (int nt = 0; nt < 16; nt++) acc1[nt] = (f32x4){0.f, 0.f, 0.f, 0.f};
#pragma unroll
  for (int s = 0; s < 4; s++) {
    const int k0 = s * 32 + koff;
    const short8 a = ld8(h2bf + (size_t)row * 128 + k0);
#pragma unroll
    for (int nt = 0; nt < 16; nt++)
      acc1[nt] = MFMA(a, ld8(W1T + (nt * 16 + r16) * 128 + k0), acc1[nt]);
  }
  unsigned short* tw_ = ts[wid];
#pragma unroll
  for (int nt = 0; nt < 16; nt++) {
    const int c = r16 + 16 * nt;
    const float bb = b1[c];
#pragma unroll
    for (int j = 0; j < 4; j++)
      tw_[(q * 4 + j) * 264 + c] = f2bf(geluf(acc1[nt][j] + bb));
  }
  __syncthreads();
  f32x4 acc2[8];
#pragma unroll
  for (int nt = 0; nt < 8; nt++) acc2[nt] = (f32x4){0.f, 0.f, 0.f, 0.f};
#pragma unroll
  for (int s = 0; s < 8; s++) {
    const int k0 = s * 32 + koff;
    const short8 a = *reinterpret_cast<const short8*>(tw_ + r16 * 264 + k0);
#pragma unroll
    for (int nt = 0; nt < 8; nt++)
      acc2[nt] = MFMA(a, ld8(W2T + (nt * 16 + r16) * 256 + k0), acc2[nt]);
  }
#pragma unroll
  for (int j = 0; j < 4; j++) {
    const int gr = r0 + q * 4 + j;
    if (gr < NN) {
#pragma unroll
      for (int nt = 0; nt < 8; nt++) {
        const int c = r16 + 16 * nt;
        outp[(size_t)gr * 128 + c] =
            out1[(size_t)gr * 128 + c] + acc2[nt][j] + b2[c];
      }
    }
  }
}

extern "C" void kernel_launch(void* const* d_in, const int* in_sizes, int n_in,
                              void* d_out, int out_size, void* d_ws,
                              size_t ws_size, hipStream_t stream) {
  (void)in_sizes; (void)n_in; (void)out_size; (void)ws_size;
  const float* x = (const float*)d_in[0];
  const float* emb = (const float*)d_in[1];
  const float* tw = (const float*)d_in[2];
  const float* mns = (const float*)d_in[3];
  const float* ln1g = (const float*)d_in[4];
  const float* ln1b = (const float*)d_in[5];
  const float* ln2g = (const float*)d_in[6];
  const float* ln2b = (const float*)d_in[7];
  const float* selfW = (const float*)d_in[8];
  const float* selfb = (const float*)d_in[9];
  const float* msgW1 = (const float*)d_in[10];
  const float* msgb1 = (const float*)d_in[11];
  const float* msgW2 = (const float*)d_in[12];
  const float* msgb2 = (const float*)d_in[13];
  const float* gateW1 = (const float*)d_in[14];
  const float* gateb1 = (const float*)d_in[15];
  const float* gateW2 = (const float*)d_in[16];
  const float* gateb2 = (const float*)d_in[17];
  const float* aggW = (const float*)d_in[18];
  const float* aggb = (const float*)d_in[19];
  const float* ffnW1 = (const float*)d_in[20];
  const float* ffnb1 = (const float*)d_in[21];
  const float* ffnW2 = (const float*)d_in[22];
  const float* ffnb2 = (const float*)d_in[23];
  const int* esrc = (const int*)d_in[24];
  const int* edst = (const int*)d_in[25];

  // ws layout (bytes):
  // hbf 0 | h2bf 12.8M | aggbf 25.6M | out1 38.4M | wts 64,000,256
  // cnt 64,360,960 | row_start 64,561,408 | cursor 64,761,600
  // bsum 64,961,792 | boff 64,962,816 | eidx 64,963,840 (+3.2M = 68.2M)
  char* ws = (char*)d_ws;
  unsigned short* hbf = (unsigned short*)(ws);
  unsigned short* h2bf = (unsigned short*)(ws + 12800000);
  unsigned short* aggbf = (unsigned short*)(ws + 25600000);
  float* out1 = (float*)(ws + 38400000);
  unsigned short* wts = (unsigned short*)(ws + 64000256);
  int* cnt = (int*)(ws + 64360960);
  int* row_start = (int*)(ws + 64561408);
  int* cursor = (int*)(ws + 64761600);
  int* bsum = (int*)(ws + 64961792);
  int* boff = (int*)(ws + 64962816);
  int* eidx = (int*)(ws + 64963840);

  float* out_nodes = (float*)d_out;
  float* out_edges = out_nodes + (size_t)NN * 128;

  const int NB_SCAN = (NN + 255) / 256;  // 196

  prep_kernel<<<704, 256, 0, stream>>>(selfW, msgW1, msgW2, gateW1, aggW,
                                       ffnW1, ffnW2, wts);
  ln_kernel<<<12500, 256, 0, stream>>>(x, ln1g, ln1b, hbf, NN);
  hipMemsetAsync(cnt, 0, 200192, stream);
  count_kernel<<<3125, 256, 0, stream>>>(edst, cnt);
  scan_sums_kernel<<<NB_SCAN, 256, 0, stream>>>(cnt, bsum);
  scan_offsets_kernel<<<1, 256, 0, stream>>>(bsum, boff, NB_SCAN);
  scan_final_kernel<<<NB_SCAN, 256, 0, stream>>>(cnt, boff, row_start, cursor);
  scatter_kernel<<<3125, 256, 0, stream>>>(edst, cursor, eidx);
  edge_kernel<<<8334, 512, 0, stream>>>(emb, tw, mns, esrc, edst, hbf, wts,
                                        msgb1, msgb2, gateb1, gateW2, gateb2,
                                        out_edges);
  agg_kernel<<<12500, 256, 0, stream>>>(row_start, eidx, out_edges,
                                        (unsigned int*)aggbf);
  node1_kernel<<<782, 256, 0, stream>>>(x, hbf, aggbf, wts, selfb, aggb, out1);
  ln_kernel<<<12500, 256, 0, stream>>>(out1, ln2g, ln2b, h2bf, NN);
  ffn_kernel<<<782, 256, 0, stream>>>(out1, h2bf, wts, ffnb1, ffnb2,
                                      out_nodes);
}

// Round 4
// 760.782 us; speedup vs baseline: 1.9354x; 1.2128x over previous
//
#include <hip/hip_runtime.h>

// TRGTMeanRelationBlock on MI355X (gfx950).
// Pipeline: prep ; ln1 ; memset(cnt) ; count ; scan x3 ; scatter(CSR) ;
//           edge (GEMMs, stores only) ; agg (CSR gather) ; node1 ; ln2 ; ffn
// Heavy GEMMs via v_mfma_f32_16x16x32_bf16.
// Fragment layouts: A/B lane l -> (row/col = l&15, 8 contiguous k at (l>>4)*8).
//                   C/D lane l -> col = l&15, row = (l>>4)*4 + reg_idx.
// Edge kernel: 64 edges/block, 8 waves x (M=64, N=16); A staged in LDS
// (XOR-swizzled); gate/msg1 share A-tile reads; epilogue transposes through
// LDS for full-line float4 stores. 43 KB LDS -> 3 blocks/CU.

typedef __attribute__((ext_vector_type(8))) short short8;
typedef __attribute__((ext_vector_type(4))) float f32x4;

#define NN 50000
#define NEDGE 800000

#define MFMA(a, b, c) __builtin_amdgcn_mfma_f32_16x16x32_bf16(a, b, c, 0, 0, 0)

__device__ __forceinline__ unsigned short f2bf(float f) {
  unsigned int u = __float_as_uint(f);
  u += 0x7fffu + ((u >> 16) & 1u);  // round-to-nearest-even
  return (unsigned short)(u >> 16);
}
// tanh-approx GELU (|err| vs exact erf-GELU < 1e-3): x*sigmoid(1.5958x(1+0.044715x^2))
__device__ __forceinline__ float geluf(float x) {
  const float s = 1.5957691216057308f * x * fmaf(0.044715f, x * x, 1.0f);
  return x * __builtin_amdgcn_rcpf(1.0f + __expf(-s));
}
__device__ __forceinline__ short8 ld8(const unsigned short* p) {
  return *reinterpret_cast<const short8*>(p);
}
__device__ __forceinline__ int swz256(int row, int byteoff) {  // 256 B rows
  return row * 256 + (byteoff ^ ((row & 15) << 4));
}
__device__ __forceinline__ int swz128(int row, int byteoff) {  // 128 B rows
  return row * 128 + (byteoff ^ ((row & 7) << 4));
}

// ---- weight prep: transpose + f32->bf16. WT[n][k] = W[k][n].
__global__ __launch_bounds__(256) void prep_kernel(
    const float* __restrict__ selfW, const float* __restrict__ msgW1,
    const float* __restrict__ msgW2, const float* __restrict__ gateW1,
    const float* __restrict__ aggW, const float* __restrict__ ffnW1,
    const float* __restrict__ ffnW2, unsigned short* __restrict__ wts) {
  const int idx = blockIdx.x * 256 + threadIdx.x;
  if (idx < 16384) {
    int n = idx >> 7, k = idx & 127;
    wts[idx] = f2bf(selfW[k * 128 + n]);
  } else if (idx < 32768) {
    int l = idx - 16384, n = l >> 7, k = l & 127;
    wts[idx] = f2bf(aggW[k * 128 + n]);
  } else if (idx < 57344) {
    int l = idx - 32768, n = l / 192, k = l - n * 192;
    wts[idx] = f2bf(msgW1[k * 128 + n]);
  } else if (idx < 73728) {
    int l = idx - 57344, n = l >> 7, k = l & 127;
    wts[idx] = f2bf(msgW2[k * 128 + n]);
  } else if (idx < 114688) {
    int l = idx - 73728, n = l / 320, k = l - n * 320;
    wts[idx] = f2bf(gateW1[k * 128 + n]);
  } else if (idx < 147456) {
    int l = idx - 114688, n = l >> 7, k = l & 127;
    wts[idx] = f2bf(ffnW1[k * 256 + n]);
  } else if (idx < 180224) {
    int l = idx - 147456, n = l >> 8, k = l & 255;
    wts[idx] = f2bf(ffnW2[k * 128 + n]);
  }
}

// ---- LayerNorm over 128 cols, one wave per row, writes bf16.
__global__ __launch_bounds__(256) void ln_kernel(
    const float* __restrict__ in, const float* __restrict__ g,
    const float* __restrict__ b, unsigned short* __restrict__ outbf,
    int nrows) {
  const int wid = threadIdx.x >> 6, lane = threadIdx.x & 63;
  const int row = blockIdx.x * 4 + wid;
  if (row >= nrows) return;
  const float2 v =
      *reinterpret_cast<const float2*>(in + (size_t)row * 128 + lane * 2);
  float s = v.x + v.y;
#pragma unroll
  for (int m = 32; m >= 1; m >>= 1) s += __shfl_xor(s, m);
  const float mean = s * 0.0078125f;
  const float dx = v.x - mean, dy = v.y - mean;
  float vs = dx * dx + dy * dy;
#pragma unroll
  for (int m = 32; m >= 1; m >>= 1) vs += __shfl_xor(vs, m);
  const float rs = rsqrtf(vs * 0.0078125f + 1e-5f);
  const float y0 = dx * rs * g[lane * 2] + b[lane * 2];
  const float y1 = dy * rs * g[lane * 2 + 1] + b[lane * 2 + 1];
  reinterpret_cast<unsigned int*>(outbf)[(size_t)row * 64 + lane] =
      (unsigned int)f2bf(y0) | ((unsigned int)f2bf(y1) << 16);
}

// ---- CSR build ----
__global__ __launch_bounds__(256) void count_kernel(
    const int* __restrict__ edst, int* __restrict__ cnt) {
  const int e = blockIdx.x * 256 + threadIdx.x;
  atomicAdd(&cnt[edst[e]], 1);
}

__global__ __launch_bounds__(256) void scan_sums_kernel(
    const int* __restrict__ cnt, int* __restrict__ bsum) {
  const int gi = blockIdx.x * 256 + threadIdx.x;
  int v = (gi < NN) ? cnt[gi] : 0;
#pragma unroll
  for (int m = 1; m < 64; m <<= 1) v += __shfl_xor(v, m);
  __shared__ int wsum[4];
  if ((threadIdx.x & 63) == 0) wsum[threadIdx.x >> 6] = v;
  __syncthreads();
  if (threadIdx.x == 0)
    bsum[blockIdx.x] = wsum[0] + wsum[1] + wsum[2] + wsum[3];
}

__global__ __launch_bounds__(256) void scan_offsets_kernel(
    const int* __restrict__ bsum, int* __restrict__ boff, int nb) {
  __shared__ int tmp[256];
  const int tid = threadIdx.x;
  const int v = (tid < nb) ? bsum[tid] : 0;
  tmp[tid] = v;
  __syncthreads();
#pragma unroll
  for (int d = 1; d < 256; d <<= 1) {
    const int t = (tid >= d) ? tmp[tid - d] : 0;
    __syncthreads();
    tmp[tid] += t;
    __syncthreads();
  }
  if (tid < nb) boff[tid] = tmp[tid] - v;  // exclusive
}

__global__ __launch_bounds__(256) void scan_final_kernel(
    const int* __restrict__ cnt, const int* __restrict__ boff,
    int* __restrict__ row_start, int* __restrict__ cursor) {
  const int tid = threadIdx.x, lane = tid & 63, wid = tid >> 6;
  const int gi = blockIdx.x * 256 + tid;
  const int val = (gi < NN) ? cnt[gi] : 0;
  int v = val;
#pragma unroll
  for (int d = 1; d < 64; d <<= 1) {
    const int t = __shfl_up(v, d);
    if (lane >= d) v += t;
  }
  __shared__ int wsum[4];
  if (lane == 63) wsum[wid] = v;
  __syncthreads();
  int woff = 0;
  for (int w = 0; w < wid; ++w) woff += wsum[w];
  const int excl = (v - val) + woff + boff[blockIdx.x];
  if (gi < NN) {
    row_start[gi] = excl;
    cursor[gi] = excl;
  }
  if (gi == NN - 1) row_start[NN] = excl + val;
}

__global__ __launch_bounds__(256) void scatter_kernel(
    const int* __restrict__ edst, int* __restrict__ cursor,
    int* __restrict__ eidx) {
  const int e = blockIdx.x * 256 + threadIdx.x;
  const int pos = atomicAdd(&cursor[edst[e]], 1);
  eidx[pos] = e;
}

// ---- edge kernel: 64 edges/block; 8 waves x (M=64, N=16); stores only.
__global__ __launch_bounds__(512, 6) void edge_kernel(
    const float* __restrict__ emb, const float* __restrict__ tw,
    const float* __restrict__ mns, const int* __restrict__ esrc,
    const int* __restrict__ edst, const unsigned short* __restrict__ hbf,
    const unsigned short* __restrict__ wts, const float* __restrict__ msgb1,
    const float* __restrict__ msgb2, const float* __restrict__ gateb1,
    const float* __restrict__ gateW2, const float* __restrict__ gateb2v,
    float* __restrict__ erout) {
  __shared__ __align__(16) unsigned short hs_s[64 * 128];     // 16 KB
  // hd (16 KB) + emb (8 KB); after GEMM2 reused as f32 transpose buf (16.9 KB)
  __shared__ __align__(16) unsigned short hdemb_s[64 * 128 + 64 * 64];
  __shared__ float p_s[8][64];
  __shared__ float G_s[64];
  __shared__ float sc_s[64];
  __shared__ int si_s[64], di_s[64];

  const int tid = threadIdx.x;
  const int wid = tid >> 6;
  const int lane = tid & 63;
  const int q = lane >> 4;
  const int r16 = lane & 15;
  const int koff = q * 8;
  const int e0 = blockIdx.x * 64;  // 12500*64 == NEDGE exactly

  const unsigned short* gateW1T = wts + 73728;  // [128][320]
  const unsigned short* msgW1T = wts + 32768;   // [128][192]
  const unsigned short* msgW2T = wts + 57344;   // [128][128]

  char* hdp = (char*)hdemb_s;           // hd tile, swz256
  char* embp = (char*)hdemb_s + 16384;  // emb tile, swz128
  float* xbuf = (float*)hdemb_s;        // f32 [32][132] transpose buffer

  // ---- phase 0: per-edge scalars
  if (tid < 64) {
    const int e = e0 + tid;
    const int si = esrc[e];
    const int di = edst[e];
    si_s[tid] = si;
    di_s[tid] = di;
    sc_s[tid] = tw[e] * 0.5f * (mns[si] + mns[di]);
  }
  __syncthreads();

  // ---- stage hs, hd (bf16 gather) and emb (f32->bf16) into LDS
#pragma unroll
  for (int r = 0; r < 2; r++) {
    const int unit = tid + 512 * r;  // 0..1023
    const int row = unit >> 4;
    const int c = unit & 15;  // 16B chunk
    const int si = si_s[row], di = di_s[row];
    *reinterpret_cast<short8*>((char*)hs_s + swz256(row, c * 16)) =
        ld8(hbf + (size_t)si * 128 + c * 8);
    *reinterpret_cast<short8*>(hdp + swz256(row, c * 16)) =
        ld8(hbf + (size_t)di * 128 + c * 8);
  }
  if (tid < 256) {
    const int row = tid >> 2, c4 = tid & 3;
    const int e = e0 + row;
#pragma unroll
    for (int i = 0; i < 4; i++) {
      const f32x4 v =
          *reinterpret_cast<const f32x4*>(emb + (size_t)e * 64 + c4 * 16 + i * 4);
      unsigned int* p = reinterpret_cast<unsigned int*>(
          embp + swz128(row, c4 * 32 + i * 8));
      p[0] = (unsigned int)f2bf(v[0]) | ((unsigned int)f2bf(v[1]) << 16);
      p[1] = (unsigned int)f2bf(v[2]) | ((unsigned int)f2bf(v[3]) << 16);
    }
  }
  __syncthreads();

  const int cc = wid * 16 + r16;  // this wave's output column

  // ---- fused K-loops. gate A=[hd(0:128)|hs(128:256)|emb(256:320)],
  //      msg1 A=[hs(0:128)|emb(128:192)] -- hs/emb A-tiles read ONCE.
  f32x4 accg[4], acc1[4];
#pragma unroll
  for (int m = 0; m < 4; m++) {
    accg[m] = (f32x4){0.f, 0.f, 0.f, 0.f};
    acc1[m] = (f32x4){0.f, 0.f, 0.f, 0.f};
  }
  // hd-only part of gate: k 0..127
#pragma unroll
  for (int s = 0; s < 4; s++) {
    const int k0 = s * 32 + koff;
    const short8 b = ld8(gateW1T + cc * 320 + k0);
#pragma unroll
    for (int m = 0; m < 4; m++) {
      const short8 a =
          *reinterpret_cast<const short8*>(hdp + swz256(m * 16 + r16, k0 * 2));
      accg[m] = MFMA(a, b, accg[m]);
    }
  }
  // shared [hs|emb] part: msg1 k0 0..191 ; gate k = 128 + k0
#pragma unroll
  for (int s = 0; s < 6; s++) {
    const int k0 = s * 32 + koff;
    const short8 bg = ld8(gateW1T + cc * 320 + 128 + k0);
    const short8 bm = ld8(msgW1T + cc * 192 + k0);
#pragma unroll
    for (int m = 0; m < 4; m++) {
      const int r = m * 16 + r16;
      short8 a;
      if (s < 4)
        a = *reinterpret_cast<const short8*>((char*)hs_s + swz256(r, k0 * 2));
      else
        a = *reinterpret_cast<const short8*>(embp + swz128(r, (k0 - 128) * 2));
      accg[m] = MFMA(a, bg, accg[m]);
      acc1[m] = MFMA(a, bm, acc1[m]);
    }
  }

  // ---- gate partials: sum over this wave's 16 cols of gelu(S+b1)*w2
  {
    const float b1 = gateb1[cc];
    const float w2 = gateW2[cc];
#pragma unroll
    for (int m = 0; m < 4; m++) {
#pragma unroll
      for (int j = 0; j < 4; j++) {
        float v = geluf(accg[m][j] + b1) * w2;
        v += __shfl_xor(v, 1);
        v += __shfl_xor(v, 2);
        v += __shfl_xor(v, 4);
        v += __shfl_xor(v, 8);
        if (r16 == 0) p_s[wid][m * 16 + q * 4 + j] = v;
      }
    }
  }
  __syncthreads();  // p_s ready; all hd reads done

  if (tid < 64) {
    float p = gateb2v[0];
#pragma unroll
    for (int w = 0; w < 8; w++) p += p_s[w][tid];
    G_s[tid] = sc_s[tid] * __builtin_amdgcn_rcpf(1.f + __expf(-p));
  }

  // ---- t1 = gelu(msg1 + b1) -> LDS (overwrites hd region), swizzled bf16
  {
    const float b1 = msgb1[cc];
#pragma unroll
    for (int m = 0; m < 4; m++) {
#pragma unroll
      for (int j = 0; j < 4; j++) {
        const int r = m * 16 + q * 4 + j;
        *reinterpret_cast<unsigned short*>(hdp + swz256(r, cc * 2)) =
            f2bf(geluf(acc1[m][j] + b1));
      }
    }
  }
  __syncthreads();  // t1 + G ready

  // ---- msg GEMM2: t1 @ msgW2, K=128
  f32x4 acc2[4];
#pragma unroll
  for (int m = 0; m < 4; m++) acc2[m] = (f32x4){0.f, 0.f, 0.f, 0.f};
#pragma unroll
  for (int s = 0; s < 4; s++) {
    const int k0 = s * 32 + koff;
    const short8 b = ld8(msgW2T + cc * 128 + k0);
#pragma unroll
    for (int m = 0; m < 4; m++) {
      const short8 a =
          *reinterpret_cast<const short8*>(hdp + swz256(m * 16 + r16, k0 * 2));
      acc2[m] = MFMA(a, b, acc2[m]);
    }
  }

  // ---- epilogue: scale, transpose via LDS, full-line float4 stores
  float vout[4][4];
  {
    const float b2 = msgb2[cc];
#pragma unroll
    for (int m = 0; m < 4; m++)
#pragma unroll
      for (int j = 0; j < 4; j++)
        vout[m][j] = G_s[m * 16 + q * 4 + j] * (acc2[m][j] + b2);
  }
  __syncthreads();  // everyone done reading t1; xbuf may overwrite
#pragma unroll
  for (int ch = 0; ch < 2; ch++) {
#pragma unroll
    for (int mm = 0; mm < 2; mm++) {
#pragma unroll
      for (int j = 0; j < 4; j++)
        xbuf[(mm * 16 + q * 4 + j) * 132 + cc] = vout[ch * 2 + mm][j];
    }
    __syncthreads();
#pragma unroll
    for (int u = 0; u < 2; u++) {
      const int unit = tid + u * 512;  // 0..1023
      const int r = unit >> 5;         // 0..31
      const int f4 = unit & 31;
      const f32x4 val = *reinterpret_cast<const f32x4*>(&xbuf[r * 132 + f4 * 4]);
      *reinterpret_cast<f32x4*>(erout + (size_t)(e0 + ch * 32 + r) * 128 +
                                f4 * 4) = val;
    }
    __syncthreads();
  }
}

// ---- aggregate: one wave per node; agg_bf16 = (sum of edge_repr)/max(deg,1)
__global__ __launch_bounds__(256) void agg_kernel(
    const int* __restrict__ row_start, const int* __restrict__ eidx,
    const float* __restrict__ er, unsigned int* __restrict__ aggbf) {
  const int wid = threadIdx.x >> 6, lane = threadIdx.x & 63;
  const int node = blockIdx.x * 4 + wid;
  const int beg = row_start[node], end = row_start[node + 1];
  float ax = 0.f, ay = 0.f;
  for (int i = beg; i < end; ++i) {
    const int e = eidx[i];
    const float2 v =
        *reinterpret_cast<const float2*>(er + (size_t)e * 128 + lane * 2);
    ax += v.x;
    ay += v.y;
  }
  const float inv = 1.0f / fmaxf((float)(end - beg), 1.0f);
  aggbf[(size_t)node * 64 + lane] =
      (unsigned int)f2bf(ax * inv) | ((unsigned int)f2bf(ay * inv) << 16);
}

// ---- node update: out1 = x + h@selfW + selfb + aggbf@aggW + aggb
__global__ __launch_bounds__(256) void node1_kernel(
    const float* __restrict__ x, const unsigned short* __restrict__ hbf,
    const unsigned short* __restrict__ aggbf,
    const unsigned short* __restrict__ wts, const float* __restrict__ selfb,
    const float* __restrict__ aggb, float* __restrict__ out1) {
  const int wid = threadIdx.x >> 6, lane = threadIdx.x & 63;
  const int q = lane >> 4, r16 = lane & 15, koff = q * 8;
  const int r0 = blockIdx.x * 64 + wid * 16;
  const int row = min(r0 + r16, NN - 1);
  const unsigned short* selfWT = wts;
  const unsigned short* aggWT = wts + 16384;
  f32x4 acc[8];
#pragma unroll
  for (int nt = 0; nt < 8; nt++) acc[nt] = (f32x4){0.f, 0.f, 0.f, 0.f};
#pragma unroll
  for (int s = 0; s < 4; s++) {
    const int k0 = s * 32 + koff;
    const short8 a1 = ld8(hbf + (size_t)row * 128 + k0);
    const short8 a2 = ld8(aggbf + (size_t)row * 128 + k0);
#pragma unroll
    for (int nt = 0; nt < 8; nt++) {
      acc[nt] = MFMA(a1, ld8(selfWT + (nt * 16 + r16) * 128 + k0), acc[nt]);
      acc[nt] = MFMA(a2, ld8(aggWT + (nt * 16 + r16) * 128 + k0), acc[nt]);
    }
  }
#pragma unroll
  for (int j = 0; j < 4; j++) {
    const int gr = r0 + q * 4 + j;
    if (gr < NN) {
#pragma unroll
      for (int nt = 0; nt < 8; nt++) {
        const int c = r16 + 16 * nt;
        out1[(size_t)gr * 128 + c] =
            x[(size_t)gr * 128 + c] + acc[nt][j] + selfb[c] + aggb[c];
      }
    }
  }
}

// ---- FFN: out = out1 + gelu(h2@W1+b1)@W2 + b2
__global__ __launch_bounds__(256) void ffn_kernel(
    const float* __restrict__ out1, const unsigned short* __restrict__ h2bf,
    const unsigned short* __restrict__ wts, const float* __restrict__ b1,
    const float* __restrict__ b2, float* __restrict__ outp) {
  __shared__ unsigned short ts[4][16 * 264];
  const int wid = threadIdx.x >> 6, lane = threadIdx.x & 63;
  const int q = lane >> 4, r16 = lane & 15, koff = q * 8;
  const int r0 = blockIdx.x * 64 + wid * 16;
  const int row = min(r0 + r16, NN - 1);
  const unsigned short* W1T = wts + 114688;  // [256][128]
  const unsigned short* W2T = wts + 147456;  // [128][256]
  f32x4 acc1[16];
#pragma unroll
  for (int nt = 0; nt < 16; nt++) acc1[nt] = (f32x4){0.f, 0.f, 0.f, 0.f};
#pragma unroll
  for (int s = 0; s < 4; s++) {
    const int k0 = s * 32 + koff;
    const short8 a = ld8(h2bf + (size_t)row * 128 + k0);
#pragma unroll
    for (int nt = 0; nt < 16; nt++)
      acc1[nt] = MFMA(a, ld8(W1T + (nt * 16 + r16) * 128 + k0), acc1[nt]);
  }
  unsigned short* tw_ = ts[wid];
#pragma unroll
  for (int nt = 0; nt < 16; nt++) {
    const int c = r16 + 16 * nt;
    const float bb = b1[c];
#pragma unroll
    for (int j = 0; j < 4; j++)
      tw_[(q * 4 + j) * 264 + c] = f2bf(geluf(acc1[nt][j] + bb));
  }
  __syncthreads();
  f32x4 acc2[8];
#pragma unroll
  for (int nt = 0; nt < 8; nt++) acc2[nt] = (f32x4){0.f, 0.f, 0.f, 0.f};
#pragma unroll
  for (int s = 0; s < 8; s++) {
    const int k0 = s * 32 + koff;
    const short8 a = *reinterpret_cast<const short8*>(tw_ + r16 * 264 + k0);
#pragma unroll
    for (int nt = 0; nt < 8; nt++)
      acc2[nt] = MFMA(a, ld8(W2T + (nt * 16 + r16) * 256 + k0), acc2[nt]);
  }
#pragma unroll
  for (int j = 0; j < 4; j++) {
    const int gr = r0 + q * 4 + j;
    if (gr < NN) {
#pragma unroll
      for (int nt = 0; nt < 8; nt++) {
        const int c = r16 + 16 * nt;
        outp[(size_t)gr * 128 + c] =
            out1[(size_t)gr * 128 + c] + acc2[nt][j] + b2[c];
      }
    }
  }
}

extern "C" void kernel_launch(void* const* d_in, const int* in_sizes, int n_in,
                              void* d_out, int out_size, void* d_ws,
                              size_t ws_size, hipStream_t stream) {
  (void)in_sizes; (void)n_in; (void)out_size; (void)ws_size;
  const float* x = (const float*)d_in[0];
  const float* emb = (const float*)d_in[1];
  const float* tw = (const float*)d_in[2];
  const float* mns = (const float*)d_in[3];
  const float* ln1g = (const float*)d_in[4];
  const float* ln1b = (const float*)d_in[5];
  const float* ln2g = (const float*)d_in[6];
  const float* ln2b = (const float*)d_in[7];
  const float* selfW = (const float*)d_in[8];
  const float* selfb = (const float*)d_in[9];
  const float* msgW1 = (const float*)d_in[10];
  const float* msgb1 = (const float*)d_in[11];
  const float* msgW2 = (const float*)d_in[12];
  const float* msgb2 = (const float*)d_in[13];
  const float* gateW1 = (const float*)d_in[14];
  const float* gateb1 = (const float*)d_in[15];
  const float* gateW2 = (const float*)d_in[16];
  const float* gateb2 = (const float*)d_in[17];
  const float* aggW = (const float*)d_in[18];
  const float* aggb = (const float*)d_in[19];
  const float* ffnW1 = (const float*)d_in[20];
  const float* ffnb1 = (const float*)d_in[21];
  const float* ffnW2 = (const float*)d_in[22];
  const float* ffnb2 = (const float*)d_in[23];
  const int* esrc = (const int*)d_in[24];
  const int* edst = (const int*)d_in[25];

  // ws layout (bytes):
  // hbf 0 | h2bf 12.8M | aggbf 25.6M | out1 38.4M | wts 64,000,256
  // cnt 64,360,960 | row_start 64,561,408 | cursor 64,761,600
  // bsum 64,961,792 | boff 64,962,816 | eidx 64,963,840 (+3.2M = 68.2M)
  char* ws = (char*)d_ws;
  unsigned short* hbf = (unsigned short*)(ws);
  unsigned short* h2bf = (unsigned short*)(ws + 12800000);
  unsigned short* aggbf = (unsigned short*)(ws + 25600000);
  float* out1 = (float*)(ws + 38400000);
  unsigned short* wts = (unsigned short*)(ws + 64000256);
  int* cnt = (int*)(ws + 64360960);
  int* row_start = (int*)(ws + 64561408);
  int* cursor = (int*)(ws + 64761600);
  int* bsum = (int*)(ws + 64961792);
  int* boff = (int*)(ws + 64962816);
  int* eidx = (int*)(ws + 64963840);

  float* out_nodes = (float*)d_out;
  float* out_edges = out_nodes + (size_t)NN * 128;

  const int NB_SCAN = (NN + 255) / 256;  // 196

  prep_kernel<<<704, 256, 0, stream>>>(selfW, msgW1, msgW2, gateW1, aggW,
                                       ffnW1, ffnW2, wts);
  ln_kernel<<<12500, 256, 0, stream>>>(x, ln1g, ln1b, hbf, NN);
  hipMemsetAsync(cnt, 0, 200192, stream);
  count_kernel<<<3125, 256, 0, stream>>>(edst, cnt);
  scan_sums_kernel<<<NB_SCAN, 256, 0, stream>>>(cnt, bsum);
  scan_offsets_kernel<<<1, 256, 0, stream>>>(bsum, boff, NB_SCAN);
  scan_final_kernel<<<NB_SCAN, 256, 0, stream>>>(cnt, boff, row_start, cursor);
  scatter_kernel<<<3125, 256, 0, stream>>>(edst, cursor, eidx);
  edge_kernel<<<12500, 512, 0, stream>>>(emb, tw, mns, esrc, edst, hbf, wts,
                                         msgb1, msgb2, gateb1, gateW2, gateb2,
                                         out_edges);
  agg_kernel<<<12500, 256, 0, stream>>>(row_start, eidx, out_edges,
                                        (unsigned int*)aggbf);
  node1_kernel<<<782, 256, 0, stream>>>(x, hbf, aggbf, wts, selfb, aggb, out1);
  ln_kernel<<<12500, 256, 0, stream>>>(out1, ln2g, ln2b, h2bf, NN);
  ffn_kernel<<<782, 256, 0, stream>>>(out1, h2bf, wts, ffnb1, ffnb2,
                                      out_nodes);
}

// Round 5
// 731.880 us; speedup vs baseline: 2.0119x; 1.0395x over previous
//
#include <hip/hip_runtime.h>

// TRGTMeanRelationBlock on MI355X (gfx950).
// Pipeline: prep ; ln1 ; node_pre(Pd,Ps,Pm) ; memset ; count ; scan x3 ;
//           scatter(CSR) ; edge ; agg ; node1 ; ln2 ; ffn
// Key factorization: gate = f(Pd[dst] + Ps[src] + emb@We), msg1 = Pm[src] + emb@Me
// where Pd/Ps/Pm are per-NODE GEMMs (h@W slices) computed once -> per-edge
// MFMA drops from K=512-equiv to K=64+64+128.
// Fragment layouts: A/B lane l -> (row/col = l&15, 8 contiguous k at (l>>4)*8).
//                   C/D lane l -> col = l&15, row = (l>>4)*4 + reg_idx.
// Edge kernel: 64 edges/block, 8 waves = 2 M-groups x 4 N-groups (M=32,N=32
// per wave) to cut LDS A-read redundancy; tiles XOR-swizzled; epilogue
// transposes through LDS for full-line float4 stores.

typedef __attribute__((ext_vector_type(8))) short short8;
typedef __attribute__((ext_vector_type(4))) float f32x4;

#define NN 50000
#define NEDGE 800000

#define MFMA(a, b, c) __builtin_amdgcn_mfma_f32_16x16x32_bf16(a, b, c, 0, 0, 0)

__device__ __forceinline__ unsigned short f2bf(float f) {
  unsigned int u = __float_as_uint(f);
  u += 0x7fffu + ((u >> 16) & 1u);  // round-to-nearest-even
  return (unsigned short)(u >> 16);
}
__device__ __forceinline__ float bf2f(unsigned short u) {
  return __uint_as_float((unsigned int)u << 16);
}
__device__ __forceinline__ unsigned int cvtpk(float a, float b) {
  unsigned int d;  // d.lo = bf16(a), d.hi = bf16(b)
  asm("v_cvt_pk_bf16_f32 %0, %1, %2" : "=v"(d) : "v"(a), "v"(b));
  return d;
}
// tanh-approx GELU (|err| vs exact erf-GELU < 1e-3)
__device__ __forceinline__ float geluf(float x) {
  const float s = 1.5957691216057308f * x * fmaf(0.044715f, x * x, 1.0f);
  return x * __builtin_amdgcn_rcpf(1.0f + __expf(-s));
}
__device__ __forceinline__ short8 ld8(const unsigned short* p) {
  return *reinterpret_cast<const short8*>(p);
}
__device__ __forceinline__ int swz256(int row, int byteoff) {  // 256 B rows
  return row * 256 + (byteoff ^ ((row & 15) << 4));
}
__device__ __forceinline__ int swz128(int row, int byteoff) {  // 128 B rows
  return row * 128 + (byteoff ^ ((row & 7) << 4));
}

// ---- weight prep: transpose + f32->bf16. WT[n][k] = W[k][n].
__global__ __launch_bounds__(256) void prep_kernel(
    const float* __restrict__ selfW, const float* __restrict__ msgW1,
    const float* __restrict__ msgW2, const float* __restrict__ gateW1,
    const float* __restrict__ aggW, const float* __restrict__ ffnW1,
    const float* __restrict__ ffnW2, unsigned short* __restrict__ wts) {
  const int idx = blockIdx.x * 256 + threadIdx.x;
  if (idx < 16384) {
    int n = idx >> 7, k = idx & 127;
    wts[idx] = f2bf(selfW[k * 128 + n]);
  } else if (idx < 32768) {
    int l = idx - 16384, n = l >> 7, k = l & 127;
    wts[idx] = f2bf(aggW[k * 128 + n]);
  } else if (idx < 57344) {
    int l = idx - 32768, n = l / 192, k = l - n * 192;
    wts[idx] = f2bf(msgW1[k * 128 + n]);
  } else if (idx < 73728) {
    int l = idx - 57344, n = l >> 7, k = l & 127;
    wts[idx] = f2bf(msgW2[k * 128 + n]);
  } else if (idx < 114688) {
    int l = idx - 73728, n = l / 320, k = l - n * 320;
    wts[idx] = f2bf(gateW1[k * 128 + n]);
  } else if (idx < 147456) {
    int l = idx - 114688, n = l >> 7, k = l & 127;
    wts[idx] = f2bf(ffnW1[k * 256 + n]);
  } else if (idx < 180224) {
    int l = idx - 147456, n = l >> 8, k = l & 255;
    wts[idx] = f2bf(ffnW2[k * 128 + n]);
  }
}

// ---- LayerNorm over 128 cols, one wave per row, writes bf16.
__global__ __launch_bounds__(256) void ln_kernel(
    const float* __restrict__ in, const float* __restrict__ g,
    const float* __restrict__ b, unsigned short* __restrict__ outbf,
    int nrows) {
  const int wid = threadIdx.x >> 6, lane = threadIdx.x & 63;
  const int row = blockIdx.x * 4 + wid;
  if (row >= nrows) return;
  const float2 v =
      *reinterpret_cast<const float2*>(in + (size_t)row * 128 + lane * 2);
  float s = v.x + v.y;
#pragma unroll
  for (int m = 32; m >= 1; m >>= 1) s += __shfl_xor(s, m);
  const float mean = s * 0.0078125f;
  const float dx = v.x - mean, dy = v.y - mean;
  float vs = dx * dx + dy * dy;
#pragma unroll
  for (int m = 32; m >= 1; m >>= 1) vs += __shfl_xor(vs, m);
  const float rs = rsqrtf(vs * 0.0078125f + 1e-5f);
  const float y0 = dx * rs * g[lane * 2] + b[lane * 2];
  const float y1 = dy * rs * g[lane * 2 + 1] + b[lane * 2 + 1];
  reinterpret_cast<unsigned int*>(outbf)[(size_t)row * 64 + lane] =
      cvtpk(y0, y1);
}

// ---- node precompute: Pd = h@Wd ; Ps = h@Ws ; Pm = h@Ms  (all bf16 out).
// Pd -> pd[node][128]; Ps/Pm interleaved -> psm[node][256] = [Ps | Pm].
__global__ __launch_bounds__(256) void node_pre_kernel(
    const unsigned short* __restrict__ hbf, const unsigned short* __restrict__ wts,
    unsigned short* __restrict__ pd, unsigned short* __restrict__ psm) {
  const int wid = threadIdx.x >> 6, lane = threadIdx.x & 63;
  const int q = lane >> 4, r16 = lane & 15, koff = q * 8;
  const int r0 = blockIdx.x * 64 + wid * 16;
  const int row = min(r0 + r16, NN - 1);
  const unsigned short* gateW1T = wts + 73728;  // [128][320]
  const unsigned short* msgW1T = wts + 32768;   // [128][192]
  f32x4 acc[3][8];
#pragma unroll
  for (int t = 0; t < 3; t++)
#pragma unroll
    for (int nt = 0; nt < 8; nt++) acc[t][nt] = (f32x4){0.f, 0.f, 0.f, 0.f};
#pragma unroll
  for (int s = 0; s < 4; s++) {
    const int k0 = s * 32 + koff;
    const short8 a = ld8(hbf + (size_t)row * 128 + k0);
#pragma unroll
    for (int nt = 0; nt < 8; nt++) {
      const int c = nt * 16 + r16;
      acc[0][nt] = MFMA(a, ld8(gateW1T + c * 320 + k0), acc[0][nt]);        // Wd
      acc[1][nt] = MFMA(a, ld8(gateW1T + c * 320 + 128 + k0), acc[1][nt]);  // Ws
      acc[2][nt] = MFMA(a, ld8(msgW1T + c * 192 + k0), acc[2][nt]);         // Ms
    }
  }
#pragma unroll
  for (int j = 0; j < 4; j++) {
    const int gr = r0 + q * 4 + j;
    if (gr < NN) {
#pragma unroll
      for (int nt = 0; nt < 8; nt++) {
        const int c = nt * 16 + r16;
        pd[(size_t)gr * 128 + c] = f2bf(acc[0][nt][j]);
        psm[(size_t)gr * 256 + c] = f2bf(acc[1][nt][j]);
        psm[(size_t)gr * 256 + 128 + c] = f2bf(acc[2][nt][j]);
      }
    }
  }
}

// ---- CSR build ----
__global__ __launch_bounds__(256) void count_kernel(
    const int* __restrict__ edst, int* __restrict__ cnt) {
  const int e = blockIdx.x * 256 + threadIdx.x;
  atomicAdd(&cnt[edst[e]], 1);
}

__global__ __launch_bounds__(256) void scan_sums_kernel(
    const int* __restrict__ cnt, int* __restrict__ bsum) {
  const int gi = blockIdx.x * 256 + threadIdx.x;
  int v = (gi < NN) ? cnt[gi] : 0;
#pragma unroll
  for (int m = 1; m < 64; m <<= 1) v += __shfl_xor(v, m);
  __shared__ int wsum[4];
  if ((threadIdx.x & 63) == 0) wsum[threadIdx.x >> 6] = v;
  __syncthreads();
  if (threadIdx.x == 0)
    bsum[blockIdx.x] = wsum[0] + wsum[1] + wsum[2] + wsum[3];
}

__global__ __launch_bounds__(256) void scan_offsets_kernel(
    const int* __restrict__ bsum, int* __restrict__ boff, int nb) {
  __shared__ int tmp[256];
  const int tid = threadIdx.x;
  const int v = (tid < nb) ? bsum[tid] : 0;
  tmp[tid] = v;
  __syncthreads();
#pragma unroll
  for (int d = 1; d < 256; d <<= 1) {
    const int t = (tid >= d) ? tmp[tid - d] : 0;
    __syncthreads();
    tmp[tid] += t;
    __syncthreads();
  }
  if (tid < nb) boff[tid] = tmp[tid] - v;  // exclusive
}

__global__ __launch_bounds__(256) void scan_final_kernel(
    const int* __restrict__ cnt, const int* __restrict__ boff,
    int* __restrict__ row_start, int* __restrict__ cursor) {
  const int tid = threadIdx.x, lane = tid & 63, wid = tid >> 6;
  const int gi = blockIdx.x * 256 + tid;
  const int val = (gi < NN) ? cnt[gi] : 0;
  int v = val;
#pragma unroll
  for (int d = 1; d < 64; d <<= 1) {
    const int t = __shfl_up(v, d);
    if (lane >= d) v += t;
  }
  __shared__ int wsum[4];
  if (lane == 63) wsum[wid] = v;
  __syncthreads();
  int woff = 0;
  for (int w = 0; w < wid; ++w) woff += wsum[w];
  const int excl = (v - val) + woff + boff[blockIdx.x];
  if (gi < NN) {
    row_start[gi] = excl;
    cursor[gi] = excl;
  }
  if (gi == NN - 1) row_start[NN] = excl + val;
}

__global__ __launch_bounds__(256) void scatter_kernel(
    const int* __restrict__ edst, int* __restrict__ cursor,
    int* __restrict__ eidx) {
  const int e = blockIdx.x * 256 + threadIdx.x;
  const int pos = atomicAdd(&cursor[edst[e]], 1);
  eidx[pos] = e;
}

// ---- edge kernel: 64 edges/block; 8 waves = 2 Mg x 4 Ng (M=32, N=32 each).
__global__ __launch_bounds__(512, 6) void edge_kernel(
    const float* __restrict__ emb, const float* __restrict__ tw,
    const float* __restrict__ mns, const int* __restrict__ esrc,
    const int* __restrict__ edst, const unsigned short* __restrict__ pd,
    const unsigned short* __restrict__ psm,
    const unsigned short* __restrict__ wts, const float* __restrict__ msgb1,
    const float* __restrict__ msgb2, const float* __restrict__ gateb1,
    const float* __restrict__ gateW2, const float* __restrict__ gateb2v,
    float* __restrict__ erout) {
  // pg 0..16384 | pm/t1 16384..32768 | emb 32768..40960 ; xbuf aliases front.
  __shared__ __align__(16) char buf[64 * 256 + 64 * 256 + 64 * 128];
  __shared__ float p_s[4][64];
  __shared__ float G_s[64];
  __shared__ float sc_s[64];
  __shared__ int si_s[64], di_s[64];

  char* pgp = buf;
  char* pmp = buf + 16384;
  char* embp = buf + 32768;
  float* xbuf = (float*)buf;  // f32 [32][132] transpose buffer (epilogue only)

  const int tid = threadIdx.x;
  const int wid = tid >> 6;
  const int lane = tid & 63;
  const int q = lane >> 4;
  const int r16 = lane & 15;
  const int koff = q * 8;
  const int mg = wid >> 2;  // 0..1  (M-group: rows mg*32..mg*32+31)
  const int ng = wid & 3;   // 0..3  (N-group: cols ng*32..ng*32+31)
  const int e0 = blockIdx.x * 64;  // 12500*64 == NEDGE exactly

  const unsigned short* gateW1T = wts + 73728;  // [128][320]
  const unsigned short* msgW1T = wts + 32768;   // [128][192]
  const unsigned short* msgW2T = wts + 57344;   // [128][128]

  // ---- phase 0: per-edge scalars
  if (tid < 64) {
    const int e = e0 + tid;
    const int si = esrc[e];
    const int di = edst[e];
    si_s[tid] = si;
    di_s[tid] = di;
    sc_s[tid] = tw[e] * 0.5f * (mns[si] + mns[di]);
  }
  __syncthreads();

  // ---- stage pg = Pd[di]+Ps[si], pm = Pm[si], emb(f32->bf16) into LDS
#pragma unroll
  for (int r = 0; r < 2; r++) {
    const int unit = tid + 512 * r;  // 0..1023 = 64 rows x 16 chunks
    const int row = unit >> 4;
    const int c = unit & 15;
    const int si = si_s[row], di = di_s[row];
    const short8 vd = ld8(pd + (size_t)di * 128 + c * 8);
    const short8 vs = ld8(psm + (size_t)si * 256 + c * 8);
    unsigned int* pg = reinterpret_cast<unsigned int*>(pgp + swz256(row, c * 16));
#pragma unroll
    for (int h = 0; h < 4; h++) {
      const float f0 = bf2f((unsigned short)vd[2 * h]) + bf2f((unsigned short)vs[2 * h]);
      const float f1 =
          bf2f((unsigned short)vd[2 * h + 1]) + bf2f((unsigned short)vs[2 * h + 1]);
      pg[h] = cvtpk(f0, f1);
    }
    *reinterpret_cast<short8*>(pmp + swz256(row, c * 16)) =
        ld8(psm + (size_t)si * 256 + 128 + c * 8);
  }
  if (tid < 256) {
    const int row = tid >> 2, c4 = tid & 3;
    const int e = e0 + row;
#pragma unroll
    for (int i = 0; i < 4; i++) {
      const f32x4 v =
          *reinterpret_cast<const f32x4*>(emb + (size_t)e * 64 + c4 * 16 + i * 4);
      unsigned int* p = reinterpret_cast<unsigned int*>(
          embp + swz128(row, c4 * 32 + i * 8));
      p[0] = cvtpk(v[0], v[1]);
      p[1] = cvtpk(v[2], v[3]);
    }
  }
  __syncthreads();

  // per-lane column constants for this wave's two 16-col slices
  int cc[2];
  float g1[2], w2[2], b1m[2], b2m[2];
#pragma unroll
  for (int i = 0; i < 2; i++) {
    cc[i] = ng * 32 + i * 16 + r16;
    g1[i] = gateb1[cc[i]];
    w2[i] = gateW2[cc[i]];
    b1m[i] = msgb1[cc[i]];
    b2m[i] = msgb2[cc[i]];
  }

  // ---- emb GEMMs: accg = emb@We (K=64), acc1 = emb@Me (K=64)
  f32x4 accg[2][2], acc1[2][2];
#pragma unroll
  for (int m = 0; m < 2; m++)
#pragma unroll
    for (int i = 0; i < 2; i++) {
      accg[m][i] = (f32x4){0.f, 0.f, 0.f, 0.f};
      acc1[m][i] = (f32x4){0.f, 0.f, 0.f, 0.f};
    }
#pragma unroll
  for (int s = 0; s < 2; s++) {
    const int k0 = s * 32 + koff;  // 0..63
    short8 a[2];
#pragma unroll
    for (int m = 0; m < 2; m++)
      a[m] = *reinterpret_cast<const short8*>(
          embp + swz128(mg * 32 + m * 16 + r16, k0 * 2));
#pragma unroll
    for (int i = 0; i < 2; i++) {
      const short8 bg = ld8(gateW1T + cc[i] * 320 + 256 + k0);
      const short8 bm = ld8(msgW1T + cc[i] * 192 + 128 + k0);
#pragma unroll
      for (int m = 0; m < 2; m++) {
        accg[m][i] = MFMA(a[m], bg, accg[m][i]);
        acc1[m][i] = MFMA(a[m], bm, acc1[m][i]);
      }
    }
  }

  // ---- gate partials over this wave's 32 cols (adds Pg from LDS pre-gelu)
#pragma unroll
  for (int m = 0; m < 2; m++) {
#pragma unroll
    for (int j = 0; j < 4; j++) {
      const int row = mg * 32 + m * 16 + q * 4 + j;
      float v = 0.f;
#pragma unroll
      for (int i = 0; i < 2; i++) {
        const float pg = bf2f(*reinterpret_cast<const unsigned short*>(
            pgp + swz256(row, cc[i] * 2)));
        v += geluf(accg[m][i][j] + pg + g1[i]) * w2[i];
      }
      v += __shfl_xor(v, 1);
      v += __shfl_xor(v, 2);
      v += __shfl_xor(v, 4);
      v += __shfl_xor(v, 8);
      if (r16 == 0) p_s[ng][row] = v;
    }
  }

  // ---- t1 = gelu(acc1 + Pm + b1) in-place in pm tile (element-exclusive)
#pragma unroll
  for (int m = 0; m < 2; m++) {
#pragma unroll
    for (int i = 0; i < 2; i++) {
#pragma unroll
      for (int j = 0; j < 4; j++) {
        const int row = mg * 32 + m * 16 + q * 4 + j;
        unsigned short* ap =
            reinterpret_cast<unsigned short*>(pmp + swz256(row, cc[i] * 2));
        const float pm = bf2f(*ap);
        *ap = f2bf(geluf(acc1[m][i][j] + pm + b1m[i]));
      }
    }
  }
  __syncthreads();  // t1 + p_s ready; pg reads done

  // ---- G combine (concurrent with GEMM2)
  if (tid < 64) {
    const float p = gateb2v[0] + p_s[0][tid] + p_s[1][tid] + p_s[2][tid] +
                    p_s[3][tid];
    G_s[tid] = sc_s[tid] * __builtin_amdgcn_rcpf(1.f + __expf(-p));
  }

  // ---- msg GEMM2: t1 @ msgW2, K=128
  f32x4 acc2[2][2];
#pragma unroll
  for (int m = 0; m < 2; m++)
#pragma unroll
    for (int i = 0; i < 2; i++) acc2[m][i] = (f32x4){0.f, 0.f, 0.f, 0.f};
#pragma unroll
  for (int s = 0; s < 4; s++) {
    const int k0 = s * 32 + koff;
    short8 a[2];
#pragma unroll
    for (int m = 0; m < 2; m++)
      a[m] = *reinterpret_cast<const short8*>(
          pmp + swz256(mg * 32 + m * 16 + r16, k0 * 2));
#pragma unroll
    for (int i = 0; i < 2; i++) {
      const short8 b = ld8(msgW2T + cc[i] * 128 + k0);
#pragma unroll
      for (int m = 0; m < 2; m++) acc2[m][i] = MFMA(a[m], b, acc2[m][i]);
    }
  }
  __syncthreads();  // G_s ready; all t1 reads done (xbuf may overwrite)

  // ---- epilogue: scale, transpose via LDS, full-line float4 stores
  float vout[2][2][4];
#pragma unroll
  for (int m = 0; m < 2; m++)
#pragma unroll
    for (int i = 0; i < 2; i++)
#pragma unroll
      for (int j = 0; j < 4; j++)
        vout[m][i][j] =
            G_s[mg * 32 + m * 16 + q * 4 + j] * (acc2[m][i][j] + b2m[i]);

#pragma unroll
  for (int ch = 0; ch < 2; ch++) {
    if (mg == ch) {
#pragma unroll
      for (int m = 0; m < 2; m++)
#pragma unroll
        for (int i = 0; i < 2; i++)
#pragma unroll
          for (int j = 0; j < 4; j++)
            xbuf[(m * 16 + q * 4 + j) * 132 + cc[i]] = vout[m][i][j];
    }
    __syncthreads();
#pragma unroll
    for (int u = 0; u < 2; u++) {
      const int unit = tid + u * 512;  // 0..1023
      const int r = unit >> 5;         // 0..31
      const int f4 = unit & 31;
      const f32x4 val = *reinterpret_cast<const f32x4*>(&xbuf[r * 132 + f4 * 4]);
      *reinterpret_cast<f32x4*>(erout + (size_t)(e0 + ch * 32 + r) * 128 +
                                f4 * 4) = val;
    }
    __syncthreads();
  }
}

// ---- aggregate: one wave per node; agg_bf16 = (sum of edge_repr)/max(deg,1)
__global__ __launch_bounds__(256) void agg_kernel(
    const int* __restrict__ row_start, const int* __restrict__ eidx,
    const float* __restrict__ er, unsigned int* __restrict__ aggbf) {
  const int wid = threadIdx.x >> 6, lane = threadIdx.x & 63;
  const int node = blockIdx.x * 4 + wid;
  const int beg = row_start[node], end = row_start[node + 1];
  float ax = 0.f, ay = 0.f, bx = 0.f, by = 0.f;
  int i = beg;
  for (; i + 2 <= end; i += 2) {
    const int ea = eidx[i], eb = eidx[i + 1];
    const float2 va =
        *reinterpret_cast<const float2*>(er + (size_t)ea * 128 + lane * 2);
    const float2 vb =
        *reinterpret_cast<const float2*>(er + (size_t)eb * 128 + lane * 2);
    ax += va.x;
    ay += va.y;
    bx += vb.x;
    by += vb.y;
  }
  if (i < end) {
    const int ea = eidx[i];
    const float2 va =
        *reinterpret_cast<const float2*>(er + (size_t)ea * 128 + lane * 2);
    ax += va.x;
    ay += va.y;
  }
  ax += bx;
  ay += by;
  const float inv = 1.0f / fmaxf((float)(end - beg), 1.0f);
  aggbf[(size_t)node * 64 + lane] = cvtpk(ax * inv, ay * inv);
}

// ---- node update: out1 = x + h@selfW + selfb + aggbf@aggW + aggb
__global__ __launch_bounds__(256) void node1_kernel(
    const float* __restrict__ x, const unsigned short* __restrict__ hbf,
    const unsigned short* __restrict__ aggbf,
    const unsigned short* __restrict__ wts, const float* __restrict__ selfb,
    const float* __restrict__ aggb, float* __restrict__ out1) {
  const int wid = threadIdx.x >> 6, lane = threadIdx.x & 63;
  const int q = lane >> 4, r16 = lane & 15, koff = q * 8;
  const int r0 = blockIdx.x * 64 + wid * 16;
  const int row = min(r0 + r16, NN - 1);
  const unsigned short* selfWT = wts;
  const unsigned short* aggWT = wts + 16384;
  f32x4 acc[8];
#pragma unroll
  for (int nt = 0; nt < 8; nt++) acc[nt] = (f32x4){0.f, 0.f, 0.f, 0.f};
#pragma unroll
  for (int s = 0; s < 4; s++) {
    const int k0 = s * 32 + koff;
    const short8 a1 = ld8(hbf + (size_t)row * 128 + k0);
    const short8 a2 = ld8(aggbf + (size_t)row * 128 + k0);
#pragma unroll
    for (int nt = 0; nt < 8; nt++) {
      acc[nt] = MFMA(a1, ld8(selfWT + (nt * 16 + r16) * 128 + k0), acc[nt]);
      acc[nt] = MFMA(a2, ld8(aggWT + (nt * 16 + r16) * 128 + k0), acc[nt]);
    }
  }
#pragma unroll
  for (int j = 0; j < 4; j++) {
    const int gr = r0 + q * 4 + j;
    if (gr < NN) {
#pragma unroll
      for (int nt = 0; nt < 8; nt++) {
        const int c = r16 + 16 * nt;
        out1[(size_t)gr * 128 + c] =
            x[(size_t)gr * 128 + c] + acc[nt][j] + selfb[c] + aggb[c];
      }
    }
  }
}

// ---- FFN: out = out1 + gelu(h2@W1+b1)@W2 + b2
__global__ __launch_bounds__(256) void ffn_kernel(
    const float* __restrict__ out1, const unsigned short* __restrict__ h2bf,
    const unsigned short* __restrict__ wts, const float* __restrict__ b1,
    const float* __restrict__ b2, float* __restrict__ outp) {
  __shared__ unsigned short ts[4][16 * 264];
  const int wid = threadIdx.x >> 6, lane = threadIdx.x & 63;
  const int q = lane >> 4, r16 = lane & 15, koff = q * 8;
  const int r0 = blockIdx.x * 64 + wid * 16;
  const int row = min(r0 + r16, NN - 1);
  const unsigned short* W1T = wts + 114688;  // [256][128]
  const unsigned short* W2T = wts + 147456;  // [128][256]
  f32x4 acc1[16];
#pragma unroll
  for (int nt = 0; nt < 16; nt++) acc1[nt] = (f32x4){0.f, 0.f, 0.f, 0.f};
#pragma unroll
  for (int s = 0; s < 4; s++) {
    const int k0 = s * 32 + koff;
    const short8 a = ld8(h2bf + (size_t)row * 128 + k0);
#pragma unroll
    for (int nt = 0; nt < 16; nt++)
      acc1[nt] = MFMA(a, ld8(W1T + (nt * 16 + r16) * 128 + k0), acc1[nt]);
  }
  unsigned short* tw_ = ts[wid];
#pragma unroll
  for (int nt = 0; nt < 16; nt++) {
    const int c = r16 + 16 * nt;
    const float bb = b1[c];
#pragma unroll
    for (int j = 0; j < 4; j++)
      tw_[(q * 4 + j) * 264 + c] = f2bf(geluf(acc1[nt][j] + bb));
  }
  __syncthreads();
  f32x4 acc2[8];
#pragma unroll
  for (int nt = 0; nt < 8; nt++) acc2[nt] = (f32x4){0.f, 0.f, 0.f, 0.f};
#pragma unroll
  for (int s = 0; s < 8; s++) {
    const int k0 = s * 32 + koff;
    const short8 a = *reinterpret_cast<const short8*>(tw_ + r16 * 264 + k0);
#pragma unroll
    for (int nt = 0; nt < 8; nt++)
      acc2[nt] = MFMA(a, ld8(W2T + (nt * 16 + r16) * 256 + k0), acc2[nt]);
  }
#pragma unroll
  for (int j = 0; j < 4; j++) {
    const int gr = r0 + q * 4 + j;
    if (gr < NN) {
#pragma unroll
      for (int nt = 0; nt < 8; nt++) {
        const int c = r16 + 16 * nt;
        outp[(size_t)gr * 128 + c] =
            out1[(size_t)gr * 128 + c] + acc2[nt][j] + b2[c];
      }
    }
  }
}

extern "C" void kernel_launch(void* const* d_in, const int* in_sizes, int n_in,
                              void* d_out, int out_size, void* d_ws,
                              size_t ws_size, hipStream_t stream) {
  (void)in_sizes; (void)n_in; (void)out_size; (void)ws_size;
  const float* x = (const float*)d_in[0];
  const float* emb = (const float*)d_in[1];
  const float* tw = (const float*)d_in[2];
  const float* mns = (const float*)d_in[3];
  const float* ln1g = (const float*)d_in[4];
  const float* ln1b = (const float*)d_in[5];
  const float* ln2g = (const float*)d_in[6];
  const float* ln2b = (const float*)d_in[7];
  const float* selfW = (const float*)d_in[8];
  const float* selfb = (const float*)d_in[9];
  const float* msgW1 = (const float*)d_in[10];
  const float* msgb1 = (const float*)d_in[11];
  const float* msgW2 = (const float*)d_in[12];
  const float* msgb2 = (const float*)d_in[13];
  const float* gateW1 = (const float*)d_in[14];
  const float* gateb1 = (const float*)d_in[15];
  const float* gateW2 = (const float*)d_in[16];
  const float* gateb2 = (const float*)d_in[17];
  const float* aggW = (const float*)d_in[18];
  const float* aggb = (const float*)d_in[19];
  const float* ffnW1 = (const float*)d_in[20];
  const float* ffnb1 = (const float*)d_in[21];
  const float* ffnW2 = (const float*)d_in[22];
  const float* ffnb2 = (const float*)d_in[23];
  const int* esrc = (const int*)d_in[24];
  const int* edst = (const int*)d_in[25];

  // ws layout (bytes); buffers with disjoint lifetimes share regions:
  // hbf 0..12.8M | Pd 12.8M..25.6M (later h2bf) | Psm 25.6M..51.2M (later
  // aggbf at 25.6M) | out1 51.2M..76.8M | wts 76.8M +360448 | cnt 77,160,448
  // | row_start 77,360,640 | cursor 77,560,832 | bsum 77,761,024 |
  // boff 77,762,048 | eidx 77,763,072 +3.2M  (~81 MB total)
  char* ws = (char*)d_ws;
  unsigned short* hbf = (unsigned short*)(ws);
  unsigned short* pdb = (unsigned short*)(ws + 12800000);
  unsigned short* h2bf = (unsigned short*)(ws + 12800000);  // after edge
  unsigned short* psmb = (unsigned short*)(ws + 25600000);
  unsigned short* aggbf = (unsigned short*)(ws + 25600000);  // after edge
  float* out1 = (float*)(ws + 51200000);
  unsigned short* wts = (unsigned short*)(ws + 76800000);
  int* cnt = (int*)(ws + 77160448);
  int* row_start = (int*)(ws + 77360640);
  int* cursor = (int*)(ws + 77560832);
  int* bsum = (int*)(ws + 77761024);
  int* boff = (int*)(ws + 77762048);
  int* eidx = (int*)(ws + 77763072);

  float* out_nodes = (float*)d_out;
  float* out_edges = out_nodes + (size_t)NN * 128;

  const int NB_SCAN = (NN + 255) / 256;  // 196

  prep_kernel<<<704, 256, 0, stream>>>(selfW, msgW1, msgW2, gateW1, aggW,
                                       ffnW1, ffnW2, wts);
  ln_kernel<<<12500, 256, 0, stream>>>(x, ln1g, ln1b, hbf, NN);
  node_pre_kernel<<<782, 256, 0, stream>>>(hbf, wts, pdb, psmb);
  hipMemsetAsync(cnt, 0, 200192, stream);
  count_kernel<<<3125, 256, 0, stream>>>(edst, cnt);
  scan_sums_kernel<<<NB_SCAN, 256, 0, stream>>>(cnt, bsum);
  scan_offsets_kernel<<<1, 256, 0, stream>>>(bsum, boff, NB_SCAN);
  scan_final_kernel<<<NB_SCAN, 256, 0, stream>>>(cnt, boff, row_start, cursor);
  scatter_kernel<<<3125, 256, 0, stream>>>(edst, cursor, eidx);
  edge_kernel<<<12500, 512, 0, stream>>>(emb, tw, mns, esrc, edst, pdb, psmb,
                                         wts, msgb1, msgb2, gateb1, gateW2,
                                         gateb2, out_edges);
  agg_kernel<<<12500, 256, 0, stream>>>(row_start, eidx, out_edges,
                                        (unsigned int*)aggbf);
  node1_kernel<<<782, 256, 0, stream>>>(x, hbf, aggbf, wts, selfb, aggb, out1);
  ln_kernel<<<12500, 256, 0, stream>>>(out1, ln2g, ln2b, h2bf, NN);
  ffn_kernel<<<782, 256, 0, stream>>>(out1, h2bf, wts, ffnb1, ffnb2,
                                      out_nodes);
}

// Round 6
// 677.944 us; speedup vs baseline: 2.1719x; 1.0796x over previous
//
#include <hip/hip_runtime.h>

// TRGTMeanRelationBlock on MI355X (gfx950).
// Pipeline: prep ; ln1 ; node_pre(Pd,Ps,Pm) ; memset(cnt, agg=d_out nodes) ;
//           count ; scan x3 ; scatter(etab CSR) ; edge (CSR-ordered, fused
//           segmented-atomic aggregation) ; node1 ; ln2 ; ffn
// Factorization: gate = f(Pd[dst]+Ps[src]+emb@We), msg1 = Pm[src]+emb@Me.
// Edge kernel consumes dst-sorted edges via etab so its epilogue can
// segment-reduce edge_repr per dst in LDS and emit few atomics (no agg pass).
// Fragment layouts: A/B lane l -> (row/col = l&15, 8 contiguous k at (l>>4)*8).
//                   C/D lane l -> col = l&15, row = (l>>4)*4 + reg_idx.

typedef __attribute__((ext_vector_type(8))) short short8;
typedef __attribute__((ext_vector_type(4))) float f32x4;

#define NN 50000
#define NEDGE 800000

#define MFMA(a, b, c) __builtin_amdgcn_mfma_f32_16x16x32_bf16(a, b, c, 0, 0, 0)

__device__ __forceinline__ unsigned short f2bf(float f) {
  unsigned int u = __float_as_uint(f);
  u += 0x7fffu + ((u >> 16) & 1u);  // round-to-nearest-even
  return (unsigned short)(u >> 16);
}
__device__ __forceinline__ float bf2f(unsigned short u) {
  return __uint_as_float((unsigned int)u << 16);
}
__device__ __forceinline__ unsigned int cvtpk(float a, float b) {
  unsigned int d;  // d.lo = bf16(a), d.hi = bf16(b)
  asm("v_cvt_pk_bf16_f32 %0, %1, %2" : "=v"(d) : "v"(a), "v"(b));
  return d;
}
// tanh-approx GELU, exp2-folded (|err| vs exact erf-GELU < 1e-3):
// gelu(x) = x * sigmoid(1.59577x(1+0.044715x^2))
//         = x / (1 + exp2(x*(-2.3022211 - 0.1029437x^2)))
__device__ __forceinline__ float geluf(float x) {
  const float t = x * fmaf(-0.1029437f, x * x, -2.3022211f);
  return x * __builtin_amdgcn_rcpf(1.0f + exp2f(t));
}
__device__ __forceinline__ short8 ld8(const unsigned short* p) {
  return *reinterpret_cast<const short8*>(p);
}
__device__ __forceinline__ int swz256(int row, int byteoff) {  // 256 B rows
  return row * 256 + (byteoff ^ ((row & 15) << 4));
}
__device__ __forceinline__ int swz128(int row, int byteoff) {  // 128 B rows
  return row * 128 + (byteoff ^ ((row & 7) << 4));
}

// ---- weight prep: transpose + f32->bf16. WT[n][k] = W[k][n].
__global__ __launch_bounds__(256) void prep_kernel(
    const float* __restrict__ selfW, const float* __restrict__ msgW1,
    const float* __restrict__ msgW2, const float* __restrict__ gateW1,
    const float* __restrict__ aggW, const float* __restrict__ ffnW1,
    const float* __restrict__ ffnW2, unsigned short* __restrict__ wts) {
  const int idx = blockIdx.x * 256 + threadIdx.x;
  if (idx < 16384) {
    int n = idx >> 7, k = idx & 127;
    wts[idx] = f2bf(selfW[k * 128 + n]);
  } else if (idx < 32768) {
    int l = idx - 16384, n = l >> 7, k = l & 127;
    wts[idx] = f2bf(aggW[k * 128 + n]);
  } else if (idx < 57344) {
    int l = idx - 32768, n = l / 192, k = l - n * 192;
    wts[idx] = f2bf(msgW1[k * 128 + n]);
  } else if (idx < 73728) {
    int l = idx - 57344, n = l >> 7, k = l & 127;
    wts[idx] = f2bf(msgW2[k * 128 + n]);
  } else if (idx < 114688) {
    int l = idx - 73728, n = l / 320, k = l - n * 320;
    wts[idx] = f2bf(gateW1[k * 128 + n]);
  } else if (idx < 147456) {
    int l = idx - 114688, n = l >> 7, k = l & 127;
    wts[idx] = f2bf(ffnW1[k * 256 + n]);
  } else if (idx < 180224) {
    int l = idx - 147456, n = l >> 8, k = l & 255;
    wts[idx] = f2bf(ffnW2[k * 128 + n]);
  }
}

// ---- LayerNorm over 128 cols, one wave per row, writes bf16.
__global__ __launch_bounds__(256) void ln_kernel(
    const float* __restrict__ in, const float* __restrict__ g,
    const float* __restrict__ b, unsigned short* __restrict__ outbf,
    int nrows) {
  const int wid = threadIdx.x >> 6, lane = threadIdx.x & 63;
  const int row = blockIdx.x * 4 + wid;
  if (row >= nrows) return;
  const float2 v =
      *reinterpret_cast<const float2*>(in + (size_t)row * 128 + lane * 2);
  float s = v.x + v.y;
#pragma unroll
  for (int m = 32; m >= 1; m >>= 1) s += __shfl_xor(s, m);
  const float mean = s * 0.0078125f;
  const float dx = v.x - mean, dy = v.y - mean;
  float vs = dx * dx + dy * dy;
#pragma unroll
  for (int m = 32; m >= 1; m >>= 1) vs += __shfl_xor(vs, m);
  const float rs = rsqrtf(vs * 0.0078125f + 1e-5f);
  const float y0 = dx * rs * g[lane * 2] + b[lane * 2];
  const float y1 = dy * rs * g[lane * 2 + 1] + b[lane * 2 + 1];
  reinterpret_cast<unsigned int*>(outbf)[(size_t)row * 64 + lane] =
      cvtpk(y0, y1);
}

// ---- node precompute: Pd = h@Wd ; Ps = h@Ws ; Pm = h@Ms  (all bf16 out).
__global__ __launch_bounds__(256) void node_pre_kernel(
    const unsigned short* __restrict__ hbf, const unsigned short* __restrict__ wts,
    unsigned short* __restrict__ pd, unsigned short* __restrict__ psm) {
  const int wid = threadIdx.x >> 6, lane = threadIdx.x & 63;
  const int q = lane >> 4, r16 = lane & 15, koff = q * 8;
  const int r0 = blockIdx.x * 64 + wid * 16;
  const int row = min(r0 + r16, NN - 1);
  const unsigned short* gateW1T = wts + 73728;  // [128][320]
  const unsigned short* msgW1T = wts + 32768;   // [128][192]
  f32x4 acc[3][8];
#pragma unroll
  for (int t = 0; t < 3; t++)
#pragma unroll
    for (int nt = 0; nt < 8; nt++) acc[t][nt] = (f32x4){0.f, 0.f, 0.f, 0.f};
#pragma unroll
  for (int s = 0; s < 4; s++) {
    const int k0 = s * 32 + koff;
    const short8 a = ld8(hbf + (size_t)row * 128 + k0);
#pragma unroll
    for (int nt = 0; nt < 8; nt++) {
      const int c = nt * 16 + r16;
      acc[0][nt] = MFMA(a, ld8(gateW1T + c * 320 + k0), acc[0][nt]);        // Wd
      acc[1][nt] = MFMA(a, ld8(gateW1T + c * 320 + 128 + k0), acc[1][nt]);  // Ws
      acc[2][nt] = MFMA(a, ld8(msgW1T + c * 192 + k0), acc[2][nt]);         // Ms
    }
  }
#pragma unroll
  for (int j = 0; j < 4; j++) {
    const int gr = r0 + q * 4 + j;
    if (gr < NN) {
#pragma unroll
      for (int nt = 0; nt < 8; nt++) {
        const int c = nt * 16 + r16;
        pd[(size_t)gr * 128 + c] = f2bf(acc[0][nt][j]);
        psm[(size_t)gr * 256 + c] = f2bf(acc[1][nt][j]);
        psm[(size_t)gr * 256 + 128 + c] = f2bf(acc[2][nt][j]);
      }
    }
  }
}

// ---- CSR build ----
__global__ __launch_bounds__(256) void count_kernel(
    const int* __restrict__ edst, int* __restrict__ cnt) {
  const int e = blockIdx.x * 256 + threadIdx.x;
  atomicAdd(&cnt[edst[e]], 1);
}

__global__ __launch_bounds__(256) void scan_sums_kernel(
    const int* __restrict__ cnt, int* __restrict__ bsum) {
  const int gi = blockIdx.x * 256 + threadIdx.x;
  int v = (gi < NN) ? cnt[gi] : 0;
#pragma unroll
  for (int m = 1; m < 64; m <<= 1) v += __shfl_xor(v, m);
  __shared__ int wsum[4];
  if ((threadIdx.x & 63) == 0) wsum[threadIdx.x >> 6] = v;
  __syncthreads();
  if (threadIdx.x == 0)
    bsum[blockIdx.x] = wsum[0] + wsum[1] + wsum[2] + wsum[3];
}

__global__ __launch_bounds__(256) void scan_offsets_kernel(
    const int* __restrict__ bsum, int* __restrict__ boff, int nb) {
  __shared__ int tmp[256];
  const int tid = threadIdx.x;
  const int v = (tid < nb) ? bsum[tid] : 0;
  tmp[tid] = v;
  __syncthreads();
#pragma unroll
  for (int d = 1; d < 256; d <<= 1) {
    const int t = (tid >= d) ? tmp[tid - d] : 0;
    __syncthreads();
    tmp[tid] += t;
    __syncthreads();
  }
  if (tid < nb) boff[tid] = tmp[tid] - v;  // exclusive
}

__global__ __launch_bounds__(256) void scan_final_kernel(
    const int* __restrict__ cnt, const int* __restrict__ boff,
    int* __restrict__ row_start, int* __restrict__ cursor) {
  const int tid = threadIdx.x, lane = tid & 63, wid = tid >> 6;
  const int gi = blockIdx.x * 256 + tid;
  const int val = (gi < NN) ? cnt[gi] : 0;
  int v = val;
#pragma unroll
  for (int d = 1; d < 64; d <<= 1) {
    const int t = __shfl_up(v, d);
    if (lane >= d) v += t;
  }
  __shared__ int wsum[4];
  if (lane == 63) wsum[wid] = v;
  __syncthreads();
  int woff = 0;
  for (int w = 0; w < wid; ++w) woff += wsum[w];
  const int excl = (v - val) + woff + boff[blockIdx.x];
  if (gi < NN) {
    row_start[gi] = excl;
    cursor[gi] = excl;
  }
  if (gi == NN - 1) row_start[NN] = excl + val;
}

// scatter: build packed per-CSR-slot edge table {e, si, di, sc}
__global__ __launch_bounds__(256) void scatter_kernel(
    const int* __restrict__ esrc, const int* __restrict__ edst,
    const float* __restrict__ tw, const float* __restrict__ mns,
    int* __restrict__ cursor, int4* __restrict__ etab) {
  const int e = blockIdx.x * 256 + threadIdx.x;
  const int si = esrc[e];
  const int di = edst[e];
  const int pos = atomicAdd(&cursor[di], 1);
  const float sc = tw[e] * 0.5f * (mns[si] + mns[di]);
  int4 v;
  v.x = e;
  v.y = si;
  v.z = di;
  v.w = __float_as_int(sc);
  etab[pos] = v;
}

// ---- edge kernel: 64 CSR-ordered edges/block; 8 waves = 2 Mg x 4 Ng
// (M=32, N=32 each); fused segmented aggregation into aggf (atomics).
__global__ __launch_bounds__(512, 6) void edge_kernel(
    const float* __restrict__ emb, const int4* __restrict__ etab,
    const unsigned short* __restrict__ pd,
    const unsigned short* __restrict__ psm,
    const unsigned short* __restrict__ wts, const float* __restrict__ msgb1,
    const float* __restrict__ msgb2, const float* __restrict__ gateb1,
    const float* __restrict__ gateW2, const float* __restrict__ gateb2v,
    float* __restrict__ erout, float* __restrict__ aggf) {
  // pg 0..16384 | pm/t1 16384..32768 | emb 32768..40960 ;
  // f32 xbuf [64][132] (33792 B) aliases pg+pm+emb-front in the epilogue.
  __shared__ __align__(16) char buf[64 * 256 + 64 * 256 + 64 * 128];
  __shared__ float p_s[4][64];
  __shared__ float G_s[64];
  __shared__ float sc_s[64];
  __shared__ int di_s[64], eidx_s[64];

  char* pgp = buf;
  char* pmp = buf + 16384;
  char* embp = buf + 32768;
  float* xbuf = (float*)buf;

  const int tid = threadIdx.x;
  const int lane = tid & 63;
  const int wid = tid >> 6;
  const int q = lane >> 4;
  const int r16 = lane & 15;
  const int koff = q * 8;
  const int mg = wid >> 2;  // 0..1
  const int ng = wid & 3;   // 0..3
  const int e0 = blockIdx.x * 64;  // CSR positions; 12500*64 == NEDGE

  const unsigned short* gateW1T = wts + 73728;  // [128][320]
  const unsigned short* msgW1T = wts + 32768;   // [128][192]
  const unsigned short* msgW2T = wts + 57344;   // [128][128]

  // ---- per-edge scalars (no barrier needed before staging: staging reads
  // etab directly; these LDS arrays are consumed only after barrier 1)
  if (tid < 64) {
    const int4 et = etab[e0 + tid];
    eidx_s[tid] = et.x;
    di_s[tid] = et.z;
    sc_s[tid] = __int_as_float(et.w);
  }

  // ---- stage pg = Pd[di]+Ps[si] (b128 writes), pm = Pm[si], emb -> bf16
#pragma unroll
  for (int r = 0; r < 2; r++) {
    const int unit = tid + 512 * r;  // 0..1023 = 64 rows x 16 chunks
    const int row = unit >> 4;
    const int c = unit & 15;
    const int4 et = etab[e0 + row];
    const int si = et.y, di = et.z;
    const short8 vd = ld8(pd + (size_t)di * 128 + c * 8);
    const short8 vs = ld8(psm + (size_t)si * 256 + c * 8);
    union { unsigned int u[4]; short8 s; } pk;
#pragma unroll
    for (int h = 0; h < 4; h++) {
      const float f0 =
          bf2f((unsigned short)vd[2 * h]) + bf2f((unsigned short)vs[2 * h]);
      const float f1 = bf2f((unsigned short)vd[2 * h + 1]) +
                       bf2f((unsigned short)vs[2 * h + 1]);
      pk.u[h] = cvtpk(f0, f1);
    }
    *reinterpret_cast<short8*>(pgp + swz256(row, c * 16)) = pk.s;
    *reinterpret_cast<short8*>(pmp + swz256(row, c * 16)) =
        ld8(psm + (size_t)si * 256 + 128 + c * 8);
  }
  if (tid < 256) {
    const int row = tid >> 2, c4 = tid & 3;
    const int e = etab[e0 + row].x;
#pragma unroll
    for (int i = 0; i < 4; i++) {
      const f32x4 v =
          *reinterpret_cast<const f32x4*>(emb + (size_t)e * 64 + c4 * 16 + i * 4);
      uint2 w;
      w.x = cvtpk(v[0], v[1]);
      w.y = cvtpk(v[2], v[3]);
      *reinterpret_cast<uint2*>(embp + swz128(row, c4 * 32 + i * 8)) = w;
    }
  }
  __syncthreads();  // (1) tiles + scalars ready

  int cc[2];
  float g1[2], w2[2], b1m[2], b2m[2];
#pragma unroll
  for (int i = 0; i < 2; i++) {
    cc[i] = ng * 32 + i * 16 + r16;
    g1[i] = gateb1[cc[i]];
    w2[i] = gateW2[cc[i]];
    b1m[i] = msgb1[cc[i]];
    b2m[i] = msgb2[cc[i]];
  }

  // ---- emb GEMMs: accg = emb@We (K=64), acc1 = emb@Me (K=64)
  f32x4 accg[2][2], acc1[2][2];
#pragma unroll
  for (int m = 0; m < 2; m++)
#pragma unroll
    for (int i = 0; i < 2; i++) {
      accg[m][i] = (f32x4){0.f, 0.f, 0.f, 0.f};
      acc1[m][i] = (f32x4){0.f, 0.f, 0.f, 0.f};
    }
#pragma unroll
  for (int s = 0; s < 2; s++) {
    const int k0 = s * 32 + koff;  // 0..63
    short8 a[2];
#pragma unroll
    for (int m = 0; m < 2; m++)
      a[m] = *reinterpret_cast<const short8*>(
          embp + swz128(mg * 32 + m * 16 + r16, k0 * 2));
#pragma unroll
    for (int i = 0; i < 2; i++) {
      const short8 bg = ld8(gateW1T + cc[i] * 320 + 256 + k0);
      const short8 bm = ld8(msgW1T + cc[i] * 192 + 128 + k0);
#pragma unroll
      for (int m = 0; m < 2; m++) {
        accg[m][i] = MFMA(a[m], bg, accg[m][i]);
        acc1[m][i] = MFMA(a[m], bm, acc1[m][i]);
      }
    }
  }

  // ---- gate partials over this wave's 32 cols (adds Pg from LDS pre-gelu)
#pragma unroll
  for (int m = 0; m < 2; m++) {
#pragma unroll
    for (int j = 0; j < 4; j++) {
      const int row = mg * 32 + m * 16 + q * 4 + j;
      float v = 0.f;
#pragma unroll
      for (int i = 0; i < 2; i++) {
        const float pg = bf2f(*reinterpret_cast<const unsigned short*>(
            pgp + swz256(row, cc[i] * 2)));
        v += geluf(accg[m][i][j] + pg + g1[i]) * w2[i];
      }
      v += __shfl_xor(v, 1);
      v += __shfl_xor(v, 2);
      v += __shfl_xor(v, 4);
      v += __shfl_xor(v, 8);
      if (r16 == 0) p_s[ng][row] = v;
    }
  }

  // ---- t1 = gelu(acc1 + Pm + b1) in-place in pm tile (element-exclusive)
#pragma unroll
  for (int m = 0; m < 2; m++) {
#pragma unroll
    for (int i = 0; i < 2; i++) {
#pragma unroll
      for (int j = 0; j < 4; j++) {
        const int row = mg * 32 + m * 16 + q * 4 + j;
        unsigned short* ap =
            reinterpret_cast<unsigned short*>(pmp + swz256(row, cc[i] * 2));
        const float pm = bf2f(*ap);
        *ap = f2bf(geluf(acc1[m][i][j] + pm + b1m[i]));
      }
    }
  }
  __syncthreads();  // (2) t1 + p_s ready; pg reads done

  // ---- G combine (runs alongside GEMM2)
  if (tid < 64) {
    const float p = gateb2v[0] + p_s[0][tid] + p_s[1][tid] + p_s[2][tid] +
                    p_s[3][tid];
    G_s[tid] =
        sc_s[tid] * __builtin_amdgcn_rcpf(1.f + exp2f(-1.4426950f * p));
  }

  // ---- msg GEMM2: t1 @ msgW2, K=128
  f32x4 acc2[2][2];
#pragma unroll
  for (int m = 0; m < 2; m++)
#pragma unroll
    for (int i = 0; i < 2; i++) acc2[m][i] = (f32x4){0.f, 0.f, 0.f, 0.f};
#pragma unroll
  for (int s = 0; s < 4; s++) {
    const int k0 = s * 32 + koff;
    short8 a[2];
#pragma unroll
    for (int m = 0; m < 2; m++)
      a[m] = *reinterpret_cast<const short8*>(
          pmp + swz256(mg * 32 + m * 16 + r16, k0 * 2));
#pragma unroll
    for (int i = 0; i < 2; i++) {
      const short8 b = ld8(msgW2T + cc[i] * 128 + k0);
#pragma unroll
      for (int m = 0; m < 2; m++) acc2[m][i] = MFMA(a[m], b, acc2[m][i]);
    }
  }
  __syncthreads();  // (3) all t1/emb reads done; G_s ready; xbuf safe

  // ---- epilogue: scale + single-pass transpose into xbuf[64][132]
#pragma unroll
  for (int m = 0; m < 2; m++)
#pragma unroll
    for (int i = 0; i < 2; i++)
#pragma unroll
      for (int j = 0; j < 4; j++) {
        const int row = mg * 32 + m * 16 + q * 4 + j;
        xbuf[row * 132 + cc[i]] = G_s[row] * (acc2[m][i][j] + b2m[i]);
      }
  __syncthreads();  // (4) xbuf complete

  // full-line float4 stores to the (original edge id) output rows
#pragma unroll
  for (int u = 0; u < 4; u++) {
    const int unit = tid + u * 512;  // 0..2047 = 64 rows x 32 f4-chunks
    const int r = unit >> 5;
    const int f4 = unit & 31;
    const f32x4 val = *reinterpret_cast<const f32x4*>(&xbuf[r * 132 + f4 * 4]);
    *reinterpret_cast<f32x4*>(erout + (size_t)eidx_s[r] * 128 + f4 * 4) = val;
  }

  // segmented column-walk aggregation (rows are dst-sorted):
  // threads 0..255 = 128 cols x 2 row-halves; ~4-6 atomic flushes per col.
  if (tid < 256) {
    const int col = tid & 127;
    const int half = tid >> 7;
    const int rbeg = half * 32, rend = rbeg + 32;
    float acc = 0.f;
    int prev = di_s[rbeg];
    for (int r = rbeg; r < rend; ++r) {
      const int d = di_s[r];
      if (d != prev) {
        atomicAdd(&aggf[(size_t)prev * 128 + col], acc);
        acc = 0.f;
        prev = d;
      }
      acc += xbuf[r * 132 + col];
    }
    atomicAdd(&aggf[(size_t)prev * 128 + col], acc);
  }
}

// ---- node update: out1 = x + h@selfW + selfb + (agg/deg)@aggW + aggb
__global__ __launch_bounds__(256) void node1_kernel(
    const float* __restrict__ x, const unsigned short* __restrict__ hbf,
    const float* __restrict__ aggf, const int* __restrict__ row_start,
    const unsigned short* __restrict__ wts, const float* __restrict__ selfb,
    const float* __restrict__ aggb, float* __restrict__ out1) {
  const int wid = threadIdx.x >> 6, lane = threadIdx.x & 63;
  const int q = lane >> 4, r16 = lane & 15, koff = q * 8;
  const int r0 = blockIdx.x * 64 + wid * 16;
  const int row = min(r0 + r16, NN - 1);
  const float inv = __builtin_amdgcn_rcpf(
      fmaxf((float)(row_start[row + 1] - row_start[row]), 1.0f));
  const unsigned short* selfWT = wts;
  const unsigned short* aggWT = wts + 16384;
  f32x4 acc[8];
#pragma unroll
  for (int nt = 0; nt < 8; nt++) acc[nt] = (f32x4){0.f, 0.f, 0.f, 0.f};
#pragma unroll
  for (int s = 0; s < 4; s++) {
    const int k0 = s * 32 + koff;
    const short8 a1 = ld8(hbf + (size_t)row * 128 + k0);
    const float* ap = aggf + (size_t)row * 128 + k0;
    const f32x4 f0 = *reinterpret_cast<const f32x4*>(ap);
    const f32x4 f1 = *reinterpret_cast<const f32x4*>(ap + 4);
    union { unsigned int u[4]; short8 s; } pk;
    pk.u[0] = cvtpk(f0[0] * inv, f0[1] * inv);
    pk.u[1] = cvtpk(f0[2] * inv, f0[3] * inv);
    pk.u[2] = cvtpk(f1[0] * inv, f1[1] * inv);
    pk.u[3] = cvtpk(f1[2] * inv, f1[3] * inv);
#pragma unroll
    for (int nt = 0; nt < 8; nt++) {
      acc[nt] = MFMA(a1, ld8(selfWT + (nt * 16 + r16) * 128 + k0), acc[nt]);
      acc[nt] = MFMA(pk.s, ld8(aggWT + (nt * 16 + r16) * 128 + k0), acc[nt]);
    }
  }
#pragma unroll
  for (int j = 0; j < 4; j++) {
    const int gr = r0 + q * 4 + j;
    if (gr < NN) {
#pragma unroll
      for (int nt = 0; nt < 8; nt++) {
        const int c = r16 + 16 * nt;
        out1[(size_t)gr * 128 + c] =
            x[(size_t)gr * 128 + c] + acc[nt][j] + selfb[c] + aggb[c];
      }
    }
  }
}

// ---- FFN: out = out1 + gelu(h2@W1+b1)@W2 + b2
__global__ __launch_bounds__(256) void ffn_kernel(
    const float* __restrict__ out1, const unsigned short* __restrict__ h2bf,
    const unsigned short* __restrict__ wts, const float* __restrict__ b1,
    const float* __restrict__ b2, float* __restrict__ outp) {
  __shared__ unsigned short ts[4][16 * 264];
  const int wid = threadIdx.x >> 6, lane = threadIdx.x & 63;
  const int q = lane >> 4, r16 = lane & 15, koff = q * 8;
  const int r0 = blockIdx.x * 64 + wid * 16;
  const int row = min(r0 + r16, NN - 1);
  const unsigned short* W1T = wts + 114688;  // [256][128]
  const unsigned short* W2T = wts + 147456;  // [128][256]
  f32x4 acc1[16];
#pragma unroll
  for (int nt = 0; nt < 16; nt++) acc1[nt] = (f32x4){0.f, 0.f, 0.f, 0.f};
#pragma unroll
  for (int s = 0; s < 4; s++) {
    const int k0 = s * 32 + koff;
    const short8 a = ld8(h2bf + (size_t)row * 128 + k0);
#pragma unroll
    for (int nt = 0; nt < 16; nt++)
      acc1[nt] = MFMA(a, ld8(W1T + (nt * 16 + r16) * 128 + k0), acc1[nt]);
  }
  unsigned short* tw_ = ts[wid];
#pragma unroll
  for (int nt = 0; nt < 16; nt++) {
    const int c = r16 + 16 * nt;
    const float bb = b1[c];
#pragma unroll
    for (int j = 0; j < 4; j++)
      tw_[(q * 4 + j) * 264 + c] = f2bf(geluf(acc1[nt][j] + bb));
  }
  __syncthreads();
  f32x4 acc2[8];
#pragma unroll
  for (int nt = 0; nt < 8; nt++) acc2[nt] = (f32x4){0.f, 0.f, 0.f, 0.f};
#pragma unroll
  for (int s = 0; s < 8; s++) {
    const int k0 = s * 32 + koff;
    const short8 a = *reinterpret_cast<const short8*>(tw_ + r16 * 264 + k0);
#pragma unroll
    for (int nt = 0; nt < 8; nt++)
      acc2[nt] = MFMA(a, ld8(W2T + (nt * 16 + r16) * 256 + k0), acc2[nt]);
  }
#pragma unroll
  for (int j = 0; j < 4; j++) {
    const int gr = r0 + q * 4 + j;
    if (gr < NN) {
#pragma unroll
      for (int nt = 0; nt < 8; nt++) {
        const int c = r16 + 16 * nt;
        outp[(size_t)gr * 128 + c] =
            out1[(size_t)gr * 128 + c] + acc2[nt][j] + b2[c];
      }
    }
  }
}

extern "C" void kernel_launch(void* const* d_in, const int* in_sizes, int n_in,
                              void* d_out, int out_size, void* d_ws,
                              size_t ws_size, hipStream_t stream) {
  (void)in_sizes; (void)n_in; (void)out_size; (void)ws_size;
  const float* x = (const float*)d_in[0];
  const float* emb = (const float*)d_in[1];
  const float* tw = (const float*)d_in[2];
  const float* mns = (const float*)d_in[3];
  const float* ln1g = (const float*)d_in[4];
  const float* ln1b = (const float*)d_in[5];
  const float* ln2g = (const float*)d_in[6];
  const float* ln2b = (const float*)d_in[7];
  const float* selfW = (const float*)d_in[8];
  const float* selfb = (const float*)d_in[9];
  const float* msgW1 = (const float*)d_in[10];
  const float* msgb1 = (const float*)d_in[11];
  const float* msgW2 = (const float*)d_in[12];
  const float* msgb2 = (const float*)d_in[13];
  const float* gateW1 = (const float*)d_in[14];
  const float* gateb1 = (const float*)d_in[15];
  const float* gateW2 = (const float*)d_in[16];
  const float* gateb2 = (const float*)d_in[17];
  const float* aggW = (const float*)d_in[18];
  const float* aggb = (const float*)d_in[19];
  const float* ffnW1 = (const float*)d_in[20];
  const float* ffnb1 = (const float*)d_in[21];
  const float* ffnW2 = (const float*)d_in[22];
  const float* ffnb2 = (const float*)d_in[23];
  const int* esrc = (const int*)d_in[24];
  const int* edst = (const int*)d_in[25];

  // ws layout (bytes):
  // hbf 0..12.8M | Pd 12.8M..25.6M (h2bf after edge) | Psm 25.6M..51.2M |
  // out1 51.2M..76.8M | wts 76.8M+360448 | cnt 77,160,448 |
  // row_start 77,360,640 | cursor 77,560,832 | bsum 77,761,024 |
  // boff 77,762,048 | etab 77,763,072 +12.8M  (~90.6 MB total)
  // agg accumulator lives in d_out's NODE region (dead until node1->ffn).
  char* ws = (char*)d_ws;
  unsigned short* hbf = (unsigned short*)(ws);
  unsigned short* pdb = (unsigned short*)(ws + 12800000);
  unsigned short* h2bf = (unsigned short*)(ws + 12800000);  // after edge
  unsigned short* psmb = (unsigned short*)(ws + 25600000);
  float* out1 = (float*)(ws + 51200000);
  unsigned short* wts = (unsigned short*)(ws + 76800000);
  int* cnt = (int*)(ws + 77160448);
  int* row_start = (int*)(ws + 77360640);
  int* cursor = (int*)(ws + 77560832);
  int* bsum = (int*)(ws + 77761024);
  int* boff = (int*)(ws + 77762048);
  int4* etab = (int4*)(ws + 77763072);

  float* out_nodes = (float*)d_out;
  float* out_edges = out_nodes + (size_t)NN * 128;
  float* aggf = out_nodes;  // reused as f32 accumulator until node1 reads it

  const int NB_SCAN = (NN + 255) / 256;  // 196

  prep_kernel<<<704, 256, 0, stream>>>(selfW, msgW1, msgW2, gateW1, aggW,
                                       ffnW1, ffnW2, wts);
  ln_kernel<<<12500, 256, 0, stream>>>(x, ln1g, ln1b, hbf, NN);
  node_pre_kernel<<<782, 256, 0, stream>>>(hbf, wts, pdb, psmb);
  hipMemsetAsync(cnt, 0, 200192, stream);
  hipMemsetAsync(aggf, 0, (size_t)NN * 128 * 4, stream);
  count_kernel<<<3125, 256, 0, stream>>>(edst, cnt);
  scan_sums_kernel<<<NB_SCAN, 256, 0, stream>>>(cnt, bsum);
  scan_offsets_kernel<<<1, 256, 0, stream>>>(bsum, boff, NB_SCAN);
  scan_final_kernel<<<NB_SCAN, 256, 0, stream>>>(cnt, boff, row_start, cursor);
  scatter_kernel<<<3125, 256, 0, stream>>>(esrc, edst, tw, mns, cursor, etab);
  edge_kernel<<<12500, 512, 0, stream>>>(emb, etab, pdb, psmb, wts, msgb1,
                                         msgb2, gateb1, gateW2, gateb2,
                                         out_edges, aggf);
  node1_kernel<<<782, 256, 0, stream>>>(x, hbf, aggf, row_start, wts, selfb,
                                        aggb, out1);
  ln_kernel<<<12500, 256, 0, stream>>>(out1, ln2g, ln2b, h2bf, NN);
  ffn_kernel<<<782, 256, 0, stream>>>(out1, h2bf, wts, ffnb1, ffnb2,
                                      out_nodes);
}

// Round 7
// 658.725 us; speedup vs baseline: 2.2353x; 1.0292x over previous
//
#include <hip/hip_runtime.h>

// TRGTMeanRelationBlock on MI355X (gfx950).
// Pipeline: prep ; node_pre(LN1 in-reg + Pd,Ps,Pm) ; memset(cnt, aggf) ;
//           count ; scan x3 ; scatter(etab CSR) ; edge (CSR-ordered, fused
//           segmented-atomic aggregation) ; node1 (LN1 in-reg) ; ffn (LN2 in-reg)
// Factorization: gate = f(Pd[dst]+Ps[src]+emb@We), msg1 = Pm[src]+emb@Me.
// LayerNorms are never materialized: kernels that need LN(x)/LN(out1) read the
// f32 rows in MFMA A-pattern and normalize in-register (shfl_xor 16/32).
// Fragment layouts: A/B lane l -> (row/col = l&15, 8 contiguous k at (l>>4)*8).
//                   C/D lane l -> col = l&15, row = (l>>4)*4 + reg_idx.

typedef __attribute__((ext_vector_type(8))) short short8;
typedef __attribute__((ext_vector_type(4))) float f32x4;

#define NN 50000
#define NEDGE 800000

#define MFMA(a, b, c) __builtin_amdgcn_mfma_f32_16x16x32_bf16(a, b, c, 0, 0, 0)

__device__ __forceinline__ unsigned short f2bf(float f) {
  unsigned int u = __float_as_uint(f);
  u += 0x7fffu + ((u >> 16) & 1u);  // round-to-nearest-even
  return (unsigned short)(u >> 16);
}
__device__ __forceinline__ float bf2f(unsigned short u) {
  return __uint_as_float((unsigned int)u << 16);
}
__device__ __forceinline__ unsigned int cvtpk(float a, float b) {
  unsigned int d;  // d.lo = bf16(a), d.hi = bf16(b)
  asm("v_cvt_pk_bf16_f32 %0, %1, %2" : "=v"(d) : "v"(a), "v"(b));
  return d;
}
// tanh-approx GELU, exp2-folded (|err| vs exact erf-GELU < 1e-3)
__device__ __forceinline__ float geluf(float x) {
  const float t = x * fmaf(-0.1029437f, x * x, -2.3022211f);
  return x * __builtin_amdgcn_rcpf(1.0f + exp2f(t));
}
__device__ __forceinline__ short8 ld8(const unsigned short* p) {
  return *reinterpret_cast<const short8*>(p);
}
__device__ __forceinline__ int swz256(int row, int byteoff) {  // 256 B rows
  return row * 256 + (byteoff ^ ((row & 15) << 4));
}
__device__ __forceinline__ int swz128(int row, int byteoff) {  // 128 B rows
  return row * 128 + (byteoff ^ ((row & 7) << 4));
}

// In-register LayerNorm over a 128-col f32 row read in MFMA A-pattern.
// Lane (q=lane>>4, r16) owns cols {s*32+q*8 .. +7 | s=0..3} of row r16-of-16.
// Mean/var reduced across the 4 q-lanes via shfl_xor 16/32. Emits bf16 A-frags.
__device__ __forceinline__ void ln_frags(const float* __restrict__ rowp,
                                         const float* __restrict__ g,
                                         const float* __restrict__ b, int koff,
                                         short8 a[4]) {
  f32x4 v[8];
#pragma unroll
  for (int s = 0; s < 4; s++) {
    v[2 * s] = *reinterpret_cast<const f32x4*>(rowp + s * 32 + koff);
    v[2 * s + 1] = *reinterpret_cast<const f32x4*>(rowp + s * 32 + koff + 4);
  }
  float sm = 0.f;
#pragma unroll
  for (int i = 0; i < 8; i++) sm += v[i][0] + v[i][1] + v[i][2] + v[i][3];
  sm += __shfl_xor(sm, 16);
  sm += __shfl_xor(sm, 32);
  const float mean = sm * 0.0078125f;
  float sq = 0.f;
#pragma unroll
  for (int i = 0; i < 8; i++) {
#pragma unroll
    for (int t = 0; t < 4; t++) {
      const float d = v[i][t] - mean;
      sq += d * d;
    }
  }
  sq += __shfl_xor(sq, 16);
  sq += __shfl_xor(sq, 32);
  const float rs = rsqrtf(sq * 0.0078125f + 1e-5f);
#pragma unroll
  for (int s = 0; s < 4; s++) {
    const f32x4 glo = *reinterpret_cast<const f32x4*>(g + s * 32 + koff);
    const f32x4 ghi = *reinterpret_cast<const f32x4*>(g + s * 32 + koff + 4);
    const f32x4 blo = *reinterpret_cast<const f32x4*>(b + s * 32 + koff);
    const f32x4 bhi = *reinterpret_cast<const f32x4*>(b + s * 32 + koff + 4);
    float y[8];
#pragma unroll
    for (int t = 0; t < 4; t++) {
      y[t] = (v[2 * s][t] - mean) * rs * glo[t] + blo[t];
      y[4 + t] = (v[2 * s + 1][t] - mean) * rs * ghi[t] + bhi[t];
    }
    union { unsigned int u[4]; short8 s8; } pk;
    pk.u[0] = cvtpk(y[0], y[1]);
    pk.u[1] = cvtpk(y[2], y[3]);
    pk.u[2] = cvtpk(y[4], y[5]);
    pk.u[3] = cvtpk(y[6], y[7]);
    a[s] = pk.s8;
  }
}

// ---- weight prep: transpose + f32->bf16. WT[n][k] = W[k][n].
__global__ __launch_bounds__(256) void prep_kernel(
    const float* __restrict__ selfW, const float* __restrict__ msgW1,
    const float* __restrict__ msgW2, const float* __restrict__ gateW1,
    const float* __restrict__ aggW, const float* __restrict__ ffnW1,
    const float* __restrict__ ffnW2, unsigned short* __restrict__ wts) {
  const int idx = blockIdx.x * 256 + threadIdx.x;
  if (idx < 16384) {
    int n = idx >> 7, k = idx & 127;
    wts[idx] = f2bf(selfW[k * 128 + n]);
  } else if (idx < 32768) {
    int l = idx - 16384, n = l >> 7, k = l & 127;
    wts[idx] = f2bf(aggW[k * 128 + n]);
  } else if (idx < 57344) {
    int l = idx - 32768, n = l / 192, k = l - n * 192;
    wts[idx] = f2bf(msgW1[k * 128 + n]);
  } else if (idx < 73728) {
    int l = idx - 57344, n = l >> 7, k = l & 127;
    wts[idx] = f2bf(msgW2[k * 128 + n]);
  } else if (idx < 114688) {
    int l = idx - 73728, n = l / 320, k = l - n * 320;
    wts[idx] = f2bf(gateW1[k * 128 + n]);
  } else if (idx < 147456) {
    int l = idx - 114688, n = l >> 7, k = l & 127;
    wts[idx] = f2bf(ffnW1[k * 256 + n]);
  } else if (idx < 180224) {
    int l = idx - 147456, n = l >> 8, k = l & 255;
    wts[idx] = f2bf(ffnW2[k * 128 + n]);
  }
}

// ---- node precompute (LN1 fused): Pd = h@Wd ; Ps = h@Ws ; Pm = h@Ms (bf16).
__global__ __launch_bounds__(256) void node_pre_kernel(
    const float* __restrict__ x, const float* __restrict__ ln1g,
    const float* __restrict__ ln1b, const unsigned short* __restrict__ wts,
    unsigned short* __restrict__ pd, unsigned short* __restrict__ psm) {
  const int wid = threadIdx.x >> 6, lane = threadIdx.x & 63;
  const int q = lane >> 4, r16 = lane & 15, koff = q * 8;
  const int r0 = blockIdx.x * 64 + wid * 16;
  const int row = min(r0 + r16, NN - 1);
  const unsigned short* gateW1T = wts + 73728;  // [128][320]
  const unsigned short* msgW1T = wts + 32768;   // [128][192]
  short8 a[4];
  ln_frags(x + (size_t)row * 128, ln1g, ln1b, koff, a);
  f32x4 acc[3][8];
#pragma unroll
  for (int t = 0; t < 3; t++)
#pragma unroll
    for (int nt = 0; nt < 8; nt++) acc[t][nt] = (f32x4){0.f, 0.f, 0.f, 0.f};
#pragma unroll
  for (int s = 0; s < 4; s++) {
    const int k0 = s * 32 + koff;
#pragma unroll
    for (int nt = 0; nt < 8; nt++) {
      const int c = nt * 16 + r16;
      acc[0][nt] = MFMA(a[s], ld8(gateW1T + c * 320 + k0), acc[0][nt]);
      acc[1][nt] = MFMA(a[s], ld8(gateW1T + c * 320 + 128 + k0), acc[1][nt]);
      acc[2][nt] = MFMA(a[s], ld8(msgW1T + c * 192 + k0), acc[2][nt]);
    }
  }
#pragma unroll
  for (int j = 0; j < 4; j++) {
    const int gr = r0 + q * 4 + j;
    if (gr < NN) {
#pragma unroll
      for (int nt = 0; nt < 8; nt++) {
        const int c = nt * 16 + r16;
        pd[(size_t)gr * 128 + c] = f2bf(acc[0][nt][j]);
        psm[(size_t)gr * 256 + c] = f2bf(acc[1][nt][j]);
        psm[(size_t)gr * 256 + 128 + c] = f2bf(acc[2][nt][j]);
      }
    }
  }
}

// ---- CSR build ----
__global__ __launch_bounds__(256) void count_kernel(
    const int* __restrict__ edst, int* __restrict__ cnt) {
  const int e = blockIdx.x * 256 + threadIdx.x;
  atomicAdd(&cnt[edst[e]], 1);
}

__global__ __launch_bounds__(256) void scan_sums_kernel(
    const int* __restrict__ cnt, int* __restrict__ bsum) {
  const int gi = blockIdx.x * 256 + threadIdx.x;
  int v = (gi < NN) ? cnt[gi] : 0;
#pragma unroll
  for (int m = 1; m < 64; m <<= 1) v += __shfl_xor(v, m);
  __shared__ int wsum[4];
  if ((threadIdx.x & 63) == 0) wsum[threadIdx.x >> 6] = v;
  __syncthreads();
  if (threadIdx.x == 0)
    bsum[blockIdx.x] = wsum[0] + wsum[1] + wsum[2] + wsum[3];
}

__global__ __launch_bounds__(256) void scan_offsets_kernel(
    const int* __restrict__ bsum, int* __restrict__ boff, int nb) {
  __shared__ int tmp[256];
  const int tid = threadIdx.x;
  const int v = (tid < nb) ? bsum[tid] : 0;
  tmp[tid] = v;
  __syncthreads();
#pragma unroll
  for (int d = 1; d < 256; d <<= 1) {
    const int t = (tid >= d) ? tmp[tid - d] : 0;
    __syncthreads();
    tmp[tid] += t;
    __syncthreads();
  }
  if (tid < nb) boff[tid] = tmp[tid] - v;  // exclusive
}

__global__ __launch_bounds__(256) void scan_final_kernel(
    const int* __restrict__ cnt, const int* __restrict__ boff,
    int* __restrict__ row_start, int* __restrict__ cursor) {
  const int tid = threadIdx.x, lane = tid & 63, wid = tid >> 6;
  const int gi = blockIdx.x * 256 + tid;
  const int val = (gi < NN) ? cnt[gi] : 0;
  int v = val;
#pragma unroll
  for (int d = 1; d < 64; d <<= 1) {
    const int t = __shfl_up(v, d);
    if (lane >= d) v += t;
  }
  __shared__ int wsum[4];
  if (lane == 63) wsum[wid] = v;
  __syncthreads();
  int woff = 0;
  for (int w = 0; w < wid; ++w) woff += wsum[w];
  const int excl = (v - val) + woff + boff[blockIdx.x];
  if (gi < NN) {
    row_start[gi] = excl;
    cursor[gi] = excl;
  }
  if (gi == NN - 1) row_start[NN] = excl + val;
}

// scatter: build packed per-CSR-slot edge table {e, si, di, sc}
__global__ __launch_bounds__(256) void scatter_kernel(
    const int* __restrict__ esrc, const int* __restrict__ edst,
    const float* __restrict__ tw, const float* __restrict__ mns,
    int* __restrict__ cursor, int4* __restrict__ etab) {
  const int e = blockIdx.x * 256 + threadIdx.x;
  const int si = esrc[e];
  const int di = edst[e];
  const int pos = atomicAdd(&cursor[di], 1);
  const float sc = tw[e] * 0.5f * (mns[si] + mns[di]);
  int4 v;
  v.x = e;
  v.y = si;
  v.z = di;
  v.w = __float_as_int(sc);
  etab[pos] = v;
}

// ---- edge kernel: 64 CSR-ordered edges/block; 8 waves = 2 Mg x 4 Ng
// (M=32, N=32 each); fused segmented aggregation into aggf (atomics).
__global__ __launch_bounds__(512, 6) void edge_kernel(
    const float* __restrict__ emb, const int4* __restrict__ etab,
    const unsigned short* __restrict__ pd,
    const unsigned short* __restrict__ psm,
    const unsigned short* __restrict__ wts, const float* __restrict__ msgb1,
    const float* __restrict__ msgb2, const float* __restrict__ gateb1,
    const float* __restrict__ gateW2, const float* __restrict__ gateb2v,
    float* __restrict__ erout, float* __restrict__ aggf) {
  // pg 0..16384 | pm/t1 16384..32768 | emb 32768..40960 ;
  // f32 xbuf [64][132] (33792 B) aliases pg+pm+emb-front in the epilogue.
  __shared__ __align__(16) char buf[64 * 256 + 64 * 256 + 64 * 128];
  __shared__ float p_s[4][64];
  __shared__ float G_s[64];
  __shared__ float sc_s[64];
  __shared__ int di_s[64], eidx_s[64];

  char* pgp = buf;
  char* pmp = buf + 16384;
  char* embp = buf + 32768;
  float* xbuf = (float*)buf;

  const int tid = threadIdx.x;
  const int lane = tid & 63;
  const int wid = tid >> 6;
  const int q = lane >> 4;
  const int r16 = lane & 15;
  const int koff = q * 8;
  const int mg = wid >> 2;  // 0..1
  const int ng = wid & 3;   // 0..3
  const int e0 = blockIdx.x * 64;  // CSR positions; 12500*64 == NEDGE

  const unsigned short* gateW1T = wts + 73728;  // [128][320]
  const unsigned short* msgW1T = wts + 32768;   // [128][192]
  const unsigned short* msgW2T = wts + 57344;   // [128][128]

  // ---- per-edge scalars (consumed only after barrier 1)
  if (tid < 64) {
    const int4 et = etab[e0 + tid];
    eidx_s[tid] = et.x;
    di_s[tid] = et.z;
    sc_s[tid] = __int_as_float(et.w);
  }

  // ---- stage pg = Pd[di]+Ps[si] (b128 writes), pm = Pm[si], emb -> bf16
#pragma unroll
  for (int r = 0; r < 2; r++) {
    const int unit = tid + 512 * r;  // 0..1023 = 64 rows x 16 chunks
    const int row = unit >> 4;
    const int c = unit & 15;
    const int4 et = etab[e0 + row];
    const int si = et.y, di = et.z;
    const short8 vd = ld8(pd + (size_t)di * 128 + c * 8);
    const short8 vs = ld8(psm + (size_t)si * 256 + c * 8);
    union { unsigned int u[4]; short8 s; } pk;
#pragma unroll
    for (int h = 0; h < 4; h++) {
      const float f0 =
          bf2f((unsigned short)vd[2 * h]) + bf2f((unsigned short)vs[2 * h]);
      const float f1 = bf2f((unsigned short)vd[2 * h + 1]) +
                       bf2f((unsigned short)vs[2 * h + 1]);
      pk.u[h] = cvtpk(f0, f1);
    }
    *reinterpret_cast<short8*>(pgp + swz256(row, c * 16)) = pk.s;
    *reinterpret_cast<short8*>(pmp + swz256(row, c * 16)) =
        ld8(psm + (size_t)si * 256 + 128 + c * 8);
  }
  if (tid < 256) {
    const int row = tid >> 2, c4 = tid & 3;
    const int e = etab[e0 + row].x;
#pragma unroll
    for (int i = 0; i < 4; i++) {
      const f32x4 v =
          *reinterpret_cast<const f32x4*>(emb + (size_t)e * 64 + c4 * 16 + i * 4);
      uint2 w;
      w.x = cvtpk(v[0], v[1]);
      w.y = cvtpk(v[2], v[3]);
      *reinterpret_cast<uint2*>(embp + swz128(row, c4 * 32 + i * 8)) = w;
    }
  }
  __syncthreads();  // (1) tiles + scalars ready

  int cc[2];
  float g1[2], w2[2], b1m[2], b2m[2];
#pragma unroll
  for (int i = 0; i < 2; i++) {
    cc[i] = ng * 32 + i * 16 + r16;
    g1[i] = gateb1[cc[i]];
    w2[i] = gateW2[cc[i]];
    b1m[i] = msgb1[cc[i]];
    b2m[i] = msgb2[cc[i]];
  }

  // ---- emb GEMMs: accg = emb@We (K=64), acc1 = emb@Me (K=64)
  f32x4 accg[2][2], acc1[2][2];
#pragma unroll
  for (int m = 0; m < 2; m++)
#pragma unroll
    for (int i = 0; i < 2; i++) {
      accg[m][i] = (f32x4){0.f, 0.f, 0.f, 0.f};
      acc1[m][i] = (f32x4){0.f, 0.f, 0.f, 0.f};
    }
#pragma unroll
  for (int s = 0; s < 2; s++) {
    const int k0 = s * 32 + koff;  // 0..63
    short8 a[2];
#pragma unroll
    for (int m = 0; m < 2; m++)
      a[m] = *reinterpret_cast<const short8*>(
          embp + swz128(mg * 32 + m * 16 + r16, k0 * 2));
#pragma unroll
    for (int i = 0; i < 2; i++) {
      const short8 bg = ld8(gateW1T + cc[i] * 320 + 256 + k0);
      const short8 bm = ld8(msgW1T + cc[i] * 192 + 128 + k0);
#pragma unroll
      for (int m = 0; m < 2; m++) {
        accg[m][i] = MFMA(a[m], bg, accg[m][i]);
        acc1[m][i] = MFMA(a[m], bm, acc1[m][i]);
      }
    }
  }

  // ---- gate partials over this wave's 32 cols (adds Pg from LDS pre-gelu)
#pragma unroll
  for (int m = 0; m < 2; m++) {
#pragma unroll
    for (int j = 0; j < 4; j++) {
      const int row = mg * 32 + m * 16 + q * 4 + j;
      float v = 0.f;
#pragma unroll
      for (int i = 0; i < 2; i++) {
        const float pg = bf2f(*reinterpret_cast<const unsigned short*>(
            pgp + swz256(row, cc[i] * 2)));
        v += geluf(accg[m][i][j] + pg + g1[i]) * w2[i];
      }
      v += __shfl_xor(v, 1);
      v += __shfl_xor(v, 2);
      v += __shfl_xor(v, 4);
      v += __shfl_xor(v, 8);
      if (r16 == 0) p_s[ng][row] = v;
    }
  }

  // ---- t1 = gelu(acc1 + Pm + b1) in-place in pm tile (element-exclusive)
#pragma unroll
  for (int m = 0; m < 2; m++) {
#pragma unroll
    for (int i = 0; i < 2; i++) {
#pragma unroll
      for (int j = 0; j < 4; j++) {
        const int row = mg * 32 + m * 16 + q * 4 + j;
        unsigned short* ap =
            reinterpret_cast<unsigned short*>(pmp + swz256(row, cc[i] * 2));
        const float pm = bf2f(*ap);
        *ap = f2bf(geluf(acc1[m][i][j] + pm + b1m[i]));
      }
    }
  }
  __syncthreads();  // (2) t1 + p_s ready; pg reads done

  // ---- G combine (runs alongside GEMM2)
  if (tid < 64) {
    const float p = gateb2v[0] + p_s[0][tid] + p_s[1][tid] + p_s[2][tid] +
                    p_s[3][tid];
    G_s[tid] =
        sc_s[tid] * __builtin_amdgcn_rcpf(1.f + exp2f(-1.4426950f * p));
  }

  // ---- msg GEMM2: t1 @ msgW2, K=128
  f32x4 acc2[2][2];
#pragma unroll
  for (int m = 0; m < 2; m++)
#pragma unroll
    for (int i = 0; i < 2; i++) acc2[m][i] = (f32x4){0.f, 0.f, 0.f, 0.f};
#pragma unroll
  for (int s = 0; s < 4; s++) {
    const int k0 = s * 32 + koff;
    short8 a[2];
#pragma unroll
    for (int m = 0; m < 2; m++)
      a[m] = *reinterpret_cast<const short8*>(
          pmp + swz256(mg * 32 + m * 16 + r16, k0 * 2));
#pragma unroll
    for (int i = 0; i < 2; i++) {
      const short8 b = ld8(msgW2T + cc[i] * 128 + k0);
#pragma unroll
      for (int m = 0; m < 2; m++) acc2[m][i] = MFMA(a[m], b, acc2[m][i]);
    }
  }
  __syncthreads();  // (3) all t1/emb reads done; G_s ready; xbuf safe

  // ---- epilogue: scale + single-pass transpose into xbuf[64][132]
#pragma unroll
  for (int m = 0; m < 2; m++)
#pragma unroll
    for (int i = 0; i < 2; i++)
#pragma unroll
      for (int j = 0; j < 4; j++) {
        const int row = mg * 32 + m * 16 + q * 4 + j;
        xbuf[row * 132 + cc[i]] = G_s[row] * (acc2[m][i][j] + b2m[i]);
      }
  __syncthreads();  // (4) xbuf complete

  // full-line float4 stores to the (original edge id) output rows
#pragma unroll
  for (int u = 0; u < 4; u++) {
    const int unit = tid + u * 512;  // 0..2047 = 64 rows x 32 f4-chunks
    const int r = unit >> 5;
    const int f4 = unit & 31;
    const f32x4 val = *reinterpret_cast<const f32x4*>(&xbuf[r * 132 + f4 * 4]);
    *reinterpret_cast<f32x4*>(erout + (size_t)eidx_s[r] * 128 + f4 * 4) = val;
  }

  // segmented column-walk aggregation (rows are dst-sorted):
  // 512 threads = 128 cols x 4 sixteen-row quarters; ~1-3 flushes per quarter.
  {
    const int col = tid & 127;
    const int qt = tid >> 7;  // 0..3
    const int rbeg = qt * 16, rend = rbeg + 16;
    float acc = 0.f;
    int prev = di_s[rbeg];
    for (int r = rbeg; r < rend; ++r) {
      const int d = di_s[r];
      if (d != prev) {
        atomicAdd(&aggf[(size_t)prev * 128 + col], acc);
        acc = 0.f;
        prev = d;
      }
      acc += xbuf[r * 132 + col];
    }
    atomicAdd(&aggf[(size_t)prev * 128 + col], acc);
  }
}

// ---- node update (LN1 in-reg): out1 = x + LN(x)@selfW + selfb
//                                      + (agg/deg)@aggW + aggb
__global__ __launch_bounds__(256) void node1_kernel(
    const float* __restrict__ x, const float* __restrict__ ln1g,
    const float* __restrict__ ln1b, const float* __restrict__ aggf,
    const int* __restrict__ row_start, const unsigned short* __restrict__ wts,
    const float* __restrict__ selfb, const float* __restrict__ aggb,
    float* __restrict__ out1) {
  const int wid = threadIdx.x >> 6, lane = threadIdx.x & 63;
  const int q = lane >> 4, r16 = lane & 15, koff = q * 8;
  const int r0 = blockIdx.x * 64 + wid * 16;
  const int row = min(r0 + r16, NN - 1);
  const float inv = __builtin_amdgcn_rcpf(
      fmaxf((float)(row_start[row + 1] - row_start[row]), 1.0f));
  const unsigned short* selfWT = wts;
  const unsigned short* aggWT = wts + 16384;
  short8 a1[4];
  ln_frags(x + (size_t)row * 128, ln1g, ln1b, koff, a1);
  f32x4 acc[8];
#pragma unroll
  for (int nt = 0; nt < 8; nt++) acc[nt] = (f32x4){0.f, 0.f, 0.f, 0.f};
#pragma unroll
  for (int s = 0; s < 4; s++) {
    const int k0 = s * 32 + koff;
    const float* ap = aggf + (size_t)row * 128 + k0;
    const f32x4 f0 = *reinterpret_cast<const f32x4*>(ap);
    const f32x4 f1 = *reinterpret_cast<const f32x4*>(ap + 4);
    union { unsigned int u[4]; short8 s; } pk;
    pk.u[0] = cvtpk(f0[0] * inv, f0[1] * inv);
    pk.u[1] = cvtpk(f0[2] * inv, f0[3] * inv);
    pk.u[2] = cvtpk(f1[0] * inv, f1[1] * inv);
    pk.u[3] = cvtpk(f1[2] * inv, f1[3] * inv);
#pragma unroll
    for (int nt = 0; nt < 8; nt++) {
      acc[nt] = MFMA(a1[s], ld8(selfWT + (nt * 16 + r16) * 128 + k0), acc[nt]);
      acc[nt] = MFMA(pk.s, ld8(aggWT + (nt * 16 + r16) * 128 + k0), acc[nt]);
    }
  }
#pragma unroll
  for (int j = 0; j < 4; j++) {
    const int gr = r0 + q * 4 + j;
    if (gr < NN) {
#pragma unroll
      for (int nt = 0; nt < 8; nt++) {
        const int c = r16 + 16 * nt;
        out1[(size_t)gr * 128 + c] =
            x[(size_t)gr * 128 + c] + acc[nt][j] + selfb[c] + aggb[c];
      }
    }
  }
}

// ---- FFN (LN2 in-reg): out = out1 + gelu(LN(out1)@W1+b1)@W2 + b2
__global__ __launch_bounds__(256) void ffn_kernel(
    const float* __restrict__ out1, const float* __restrict__ ln2g,
    const float* __restrict__ ln2b, const unsigned short* __restrict__ wts,
    const float* __restrict__ b1, const float* __restrict__ b2,
    float* __restrict__ outp) {
  __shared__ unsigned short ts[4][16 * 264];
  const int wid = threadIdx.x >> 6, lane = threadIdx.x & 63;
  const int q = lane >> 4, r16 = lane & 15, koff = q * 8;
  const int r0 = blockIdx.x * 64 + wid * 16;
  const int row = min(r0 + r16, NN - 1);
  const unsigned short* W1T = wts + 114688;  // [256][128]
  const unsigned short* W2T = wts + 147456;  // [128][256]
  short8 a[4];
  ln_frags(out1 + (size_t)row * 128, ln2g, ln2b, koff, a);
  f32x4 acc1[16];
#pragma unroll
  for (int nt = 0; nt < 16; nt++) acc1[nt] = (f32x4){0.f, 0.f, 0.f, 0.f};
#pragma unroll
  for (int s = 0; s < 4; s++) {
    const int k0 = s * 32 + koff;
#pragma unroll
    for (int nt = 0; nt < 16; nt++)
      acc1[nt] = MFMA(a[s], ld8(W1T + (nt * 16 + r16) * 128 + k0), acc1[nt]);
  }
  unsigned short* tw_ = ts[wid];
#pragma unroll
  for (int nt = 0; nt < 16; nt++) {
    const int c = r16 + 16 * nt;
    const float bb = b1[c];
#pragma unroll
    for (int j = 0; j < 4; j++)
      tw_[(q * 4 + j) * 264 + c] = f2bf(geluf(acc1[nt][j] + bb));
  }
  __syncthreads();
  f32x4 acc2[8];
#pragma unroll
  for (int nt = 0; nt < 8; nt++) acc2[nt] = (f32x4){0.f, 0.f, 0.f, 0.f};
#pragma unroll
  for (int s = 0; s < 8; s++) {
    const int k0 = s * 32 + koff;
    const short8 av = *reinterpret_cast<const short8*>(tw_ + r16 * 264 + k0);
#pragma unroll
    for (int nt = 0; nt < 8; nt++)
      acc2[nt] = MFMA(av, ld8(W2T + (nt * 16 + r16) * 256 + k0), acc2[nt]);
  }
#pragma unroll
  for (int j = 0; j < 4; j++) {
    const int gr = r0 + q * 4 + j;
    if (gr < NN) {
#pragma unroll
      for (int nt = 0; nt < 8; nt++) {
        const int c = r16 + 16 * nt;
        outp[(size_t)gr * 128 + c] =
            out1[(size_t)gr * 128 + c] + acc2[nt][j] + b2[c];
      }
    }
  }
}

extern "C" void kernel_launch(void* const* d_in, const int* in_sizes, int n_in,
                              void* d_out, int out_size, void* d_ws,
                              size_t ws_size, hipStream_t stream) {
  (void)in_sizes; (void)n_in; (void)out_size; (void)ws_size;
  const float* x = (const float*)d_in[0];
  const float* emb = (const float*)d_in[1];
  const float* tw = (const float*)d_in[2];
  const float* mns = (const float*)d_in[3];
  const float* ln1g = (const float*)d_in[4];
  const float* ln1b = (const float*)d_in[5];
  const float* ln2g = (const float*)d_in[6];
  const float* ln2b = (const float*)d_in[7];
  const float* selfW = (const float*)d_in[8];
  const float* selfb = (const float*)d_in[9];
  const float* msgW1 = (const float*)d_in[10];
  const float* msgb1 = (const float*)d_in[11];
  const float* msgW2 = (const float*)d_in[12];
  const float* msgb2 = (const float*)d_in[13];
  const float* gateW1 = (const float*)d_in[14];
  const float* gateb1 = (const float*)d_in[15];
  const float* gateW2 = (const float*)d_in[16];
  const float* gateb2 = (const float*)d_in[17];
  const float* aggW = (const float*)d_in[18];
  const float* aggb = (const float*)d_in[19];
  const float* ffnW1 = (const float*)d_in[20];
  const float* ffnb1 = (const float*)d_in[21];
  const float* ffnW2 = (const float*)d_in[22];
  const float* ffnb2 = (const float*)d_in[23];
  const int* esrc = (const int*)d_in[24];
  const int* edst = (const int*)d_in[25];

  // ws layout (bytes):
  // Pd 0..12.8M | Psm 25.6M..51.2M | out1 51.2M..76.8M | wts 76.8M+360448 |
  // cnt 77,160,448 | row_start 77,360,640 | cursor 77,560,832 |
  // bsum 77,761,024 | boff 77,762,048 | etab 77,763,072 +12.8M (~90.6 MB)
  // agg accumulator lives in d_out's NODE region (dead until node1 reads it).
  char* ws = (char*)d_ws;
  unsigned short* pdb = (unsigned short*)(ws);
  unsigned short* psmb = (unsigned short*)(ws + 25600000);
  float* out1 = (float*)(ws + 51200000);
  unsigned short* wts = (unsigned short*)(ws + 76800000);
  int* cnt = (int*)(ws + 77160448);
  int* row_start = (int*)(ws + 77360640);
  int* cursor = (int*)(ws + 77560832);
  int* bsum = (int*)(ws + 77761024);
  int* boff = (int*)(ws + 77762048);
  int4* etab = (int4*)(ws + 77763072);

  float* out_nodes = (float*)d_out;
  float* out_edges = out_nodes + (size_t)NN * 128;
  float* aggf = out_nodes;  // reused as f32 accumulator until node1 reads it

  const int NB_SCAN = (NN + 255) / 256;  // 196

  prep_kernel<<<704, 256, 0, stream>>>(selfW, msgW1, msgW2, gateW1, aggW,
                                       ffnW1, ffnW2, wts);
  node_pre_kernel<<<782, 256, 0, stream>>>(x, ln1g, ln1b, wts, pdb, psmb);
  hipMemsetAsync(cnt, 0, 200192, stream);
  hipMemsetAsync(aggf, 0, (size_t)NN * 128 * 4, stream);
  count_kernel<<<3125, 256, 0, stream>>>(edst, cnt);
  scan_sums_kernel<<<NB_SCAN, 256, 0, stream>>>(cnt, bsum);
  scan_offsets_kernel<<<1, 256, 0, stream>>>(bsum, boff, NB_SCAN);
  scan_final_kernel<<<NB_SCAN, 256, 0, stream>>>(cnt, boff, row_start, cursor);
  scatter_kernel<<<3125, 256, 0, stream>>>(esrc, edst, tw, mns, cursor, etab);
  edge_kernel<<<12500, 512, 0, stream>>>(emb, etab, pdb, psmb, wts, msgb1,
                                         msgb2, gateb1, gateW2, gateb2,
                                         out_edges, aggf);
  node1_kernel<<<782, 256, 0, stream>>>(x, ln1g, ln1b, aggf, row_start, wts,
                                        selfb, aggb, out1);
  ffn_kernel<<<782, 256, 0, stream>>>(out1, ln2g, ln2b, wts, ffnb1, ffnb2,
                                      out_nodes);
}